// Round 10
// baseline (658.946 us; speedup 1.0000x reference)
//
#include <hip/hip_runtime.h>
#include <cstdint>

// ---------------------------------------------------------------------------
// LaSSMDecoder on MI355X — Round 10:
//  (a) KNN reverted to 1 query/block (round-8 shape; round-9's 4-query tiling
//      dropped occupancy 60→18% and serialized inserts). Float compares
//      (same order as uint keys), pointer-increment addressing.
//  (b) MFMA GEMM tile 128x64 → 128x128: MFMA:ds ratio 2:1 → 3:1, 40KB LDS.
//  (c) producer-side fp32->(hi,lo) bf16 split fusions kept (round 9).
// ---------------------------------------------------------------------------

typedef __attribute__((ext_vector_type(8))) short bf16x8;
typedef __attribute__((ext_vector_type(4))) float f32x4;

__device__ __forceinline__ unsigned short f2bf(float f) {
  unsigned int u = __float_as_uint(f);
  u += 0x7fff + ((u >> 16) & 1);        // RNE
  return (unsigned short)(u >> 16);
}
__device__ __forceinline__ float bf2f(unsigned short h) {
  return __uint_as_float(((unsigned int)h) << 16);
}

// -------------------------- fp32 -> (hi, lo) bf16 planes -------------------
__global__ __launch_bounds__(256) void cvt_kernel(
    const float* __restrict__ src, unsigned short* __restrict__ hi,
    unsigned short* __restrict__ lo, int n4)
{
  const int i = blockIdx.x*256 + threadIdx.x;
  if (i < n4) {
    const float4 v = ((const float4*)src)[i];
    const unsigned short h0=f2bf(v.x), h1=f2bf(v.y), h2=f2bf(v.z), h3=f2bf(v.w);
    const unsigned short l0=f2bf(v.x-bf2f(h0)), l1=f2bf(v.y-bf2f(h1)),
                         l2=f2bf(v.z-bf2f(h2)), l3=f2bf(v.w-bf2f(h3));
    ((uint2*)hi)[i] = make_uint2((unsigned)h0 | ((unsigned)h1<<16),
                                 (unsigned)h2 | ((unsigned)h3<<16));
    ((uint2*)lo)[i] = make_uint2((unsigned)l0 | ((unsigned)l1<<16),
                                 (unsigned)l2 | ((unsigned)l3<<16));
  }
}

// ---------------- wave-uniform top-8 list in named registers (float keys) --
__device__ __forceinline__ bool flex_less(float d, int i, float dr, int ir) {
  return d < dr || (d == dr && i < ir);
}

// strict-key insert: arrival order ascending -> ties keep earlier index
#define KNN_INS_F(dv, iv)                                                      \
  do {                                                                         \
    const float _d = (dv); const int _v = (iv);                                \
    const bool a0 = _d < bd0;                                                  \
    const bool a1 = _d < bd1;                                                  \
    const bool a2 = _d < bd2;                                                  \
    const bool a3 = _d < bd3;                                                  \
    const bool a4 = _d < bd4;                                                  \
    const bool a5 = _d < bd5;                                                  \
    const bool a6 = _d < bd6;                                                  \
    bd7 = a6 ? bd6 : _d;              id7 = a6 ? id6 : _v;                     \
    bd6 = a5 ? bd5 : (a6 ? _d : bd6); id6 = a5 ? id5 : (a6 ? _v : id6);        \
    bd5 = a4 ? bd4 : (a5 ? _d : bd5); id5 = a4 ? id4 : (a5 ? _v : id5);        \
    bd4 = a3 ? bd3 : (a4 ? _d : bd4); id4 = a3 ? id3 : (a4 ? _v : id4);        \
    bd3 = a2 ? bd2 : (a3 ? _d : bd3); id3 = a2 ? id2 : (a3 ? _v : id3);        \
    bd2 = a1 ? bd1 : (a2 ? _d : bd2); id2 = a1 ? id1 : (a2 ? _v : id2);        \
    bd1 = a0 ? bd0 : (a1 ? _d : bd1); id1 = a0 ? id0 : (a1 ? _v : id1);        \
    bd0 = a0 ? _d : bd0;              id0 = a0 ? _v : id0;                     \
  } while (0)

// lexicographic insert (cross-wave merge); caller pre-qualifies vs slot 7
#define KNN_INS_FLEX(dv, iv)                                                   \
  do {                                                                         \
    const float _d = (dv); const int _v = (iv);                                \
    const bool a0 = flex_less(_d, _v, bd0, id0);                               \
    const bool a1 = flex_less(_d, _v, bd1, id1);                               \
    const bool a2 = flex_less(_d, _v, bd2, id2);                               \
    const bool a3 = flex_less(_d, _v, bd3, id3);                               \
    const bool a4 = flex_less(_d, _v, bd4, id4);                               \
    const bool a5 = flex_less(_d, _v, bd5, id5);                               \
    const bool a6 = flex_less(_d, _v, bd6, id6);                               \
    bd7 = a6 ? bd6 : _d;              id7 = a6 ? id6 : _v;                     \
    bd6 = a5 ? bd5 : (a6 ? _d : bd6); id6 = a5 ? id5 : (a6 ? _v : id6);        \
    bd5 = a4 ? bd4 : (a5 ? _d : bd5); id5 = a4 ? id4 : (a5 ? _v : id5);        \
    bd4 = a3 ? bd3 : (a4 ? _d : bd4); id4 = a3 ? id3 : (a4 ? _v : id4);        \
    bd3 = a2 ? bd2 : (a3 ? _d : bd3); id3 = a2 ? id2 : (a3 ? _v : id3);        \
    bd2 = a1 ? bd1 : (a2 ? _d : bd2); id2 = a1 ? id1 : (a2 ? _v : id2);        \
    bd1 = a0 ? bd0 : (a1 ? _d : bd1); id1 = a0 ? id0 : (a1 ? _v : id1);        \
    bd0 = a0 ? _d : bd0;              id0 = a0 ? _v : id0;                     \
  } while (0)

#define KNN_RESET_F()                                                          \
  do {                                                                         \
    bd0=bd1=bd2=bd3=bd4=bd5=bd6=bd7 = 3.4e38f;                                 \
    id0=id1=id2=id3=id4=id5=id6=id7 = 0x7fffffff;                              \
  } while (0)

// -------------------------- prep: pack (sx,sy,sz,|s|^2) as float4 ----------
__global__ void prep_kernel(const float* __restrict__ spos,
                            float4* __restrict__ P4)
{
#pragma clang fp contract(off)
  const int n = blockIdx.x*256 + threadIdx.x;
  if (n < 32768) {
    const float sx = spos[n*3+0], sy = spos[n*3+1], sz = spos[n*3+2];
    P4[n] = make_float4(sx, sy, sz, sx*sx + sy*sy + sz*sz);
  }
}

// -------------------------- KNN: 1 query / block, 4 waves ------------------
__global__ __launch_bounds__(256) void knn_kernel(
    const float* __restrict__ qpos, const float4* __restrict__ P4,
    int* __restrict__ idx_out)
{
#pragma clang fp contract(off)
  __shared__ float skey[32];
  __shared__ int   sidx[32];
  const int q = blockIdx.x, tid = threadIdx.x;
  const int wave = tid >> 6, lane = tid & 63;
  const float qx = qpos[q*3+0], qy = qpos[q*3+1], qz = qpos[q*3+2];
  const float qq = qx*qx + qy*qy + qz*qz;
  float bd0,bd1,bd2,bd3,bd4,bd5,bd6,bd7;
  int   id0,id1,id2,id3,id4,id5,id6,id7;
  KNN_RESET_F();
  const float4* pp = P4 + (wave << 13) + lane;   // 8192 pts per wave
  int nb = (wave << 13);
  for (int it = 0; it < 128; ++it) {
    const float4 p = *pp;  pp += 64;
    const float d2 = (qq + p.w) - 2.0f*(qx*p.x + qy*p.y + qz*p.z);  // exact ref formula
    unsigned long long m = __ballot(d2 < bd7);
    while (m) {
      const int l = __ffsll(m) - 1;
      m &= m - 1;
      const float dk = __shfl(d2, l);
      if (dk < bd7) KNN_INS_F(dk, nb + l);
    }
    nb += 64;
  }
  if (lane == 0) {
    const int o = wave*8;
    skey[o+0]=bd0; skey[o+1]=bd1; skey[o+2]=bd2; skey[o+3]=bd3;
    skey[o+4]=bd4; skey[o+5]=bd5; skey[o+6]=bd6; skey[o+7]=bd7;
    sidx[o+0]=id0; sidx[o+1]=id1; sidx[o+2]=id2; sidx[o+3]=id3;
    sidx[o+4]=id4; sidx[o+5]=id5; sidx[o+6]=id6; sidx[o+7]=id7;
  }
  __syncthreads();
  if (tid == 0) {
    KNN_RESET_F();
    for (int s = 0; s < 32; ++s) {
      const float dk = skey[s];
      const int   ui = sidx[s];
      if (flex_less(dk, ui, bd7, id7)) KNN_INS_FLEX(dk, ui);
    }
    idx_out[q*8+0]=id0; idx_out[q*8+1]=id1; idx_out[q*8+2]=id2; idx_out[q*8+3]=id3;
    idx_out[q*8+4]=id4; idx_out[q*8+5]=id5; idx_out[q*8+6]=id6; idx_out[q*8+7]=id7;
  }
}

// -------------------------- inverse permutation ----------------------------
__global__ void inv_kernel(const int* __restrict__ order, int* __restrict__ inv)
{
  int i = blockIdx.x*blockDim.x + threadIdx.x;
  if (i < 4096) { int b = i >> 11, t = i & 2047; inv[(b<<11) + order[i]] = t; }
}

// -------------------------- MFMA GEMM on pre-split bf16 planes -------------
// Y = act(A[rowmap] @ Wt^T + b); optional (Yh,Yl) plane output instead of Y.
// Tile 128x128, 4 waves (2x2, 64x64 each = 4x4 frags of 16x16x32), BK=32.
// LDS = 4 x 128x40 shorts = 40 KB. M % 128 == 0, Kd % 32 == 0; Nn guarded.
#define GBM 128
#define GBN 128
#define GBK 32
#define GLDK 40   // padded LDS row length (bf16 units): 32 + 8
__global__ __launch_bounds__(256) void gemm_mfma(
    const unsigned short* __restrict__ Ahp, const unsigned short* __restrict__ Alp,
    const int* __restrict__ rowmap,
    const unsigned short* __restrict__ Bhp, const unsigned short* __restrict__ Blp,
    const float* __restrict__ bias,
    float* __restrict__ Y,
    unsigned short* __restrict__ Yh, unsigned short* __restrict__ Yl,
    int M, int Nn, int Kd, int act)
{
  __shared__ unsigned short Ah[GBM*GLDK], Al[GBM*GLDK];
  __shared__ unsigned short Bh[GBN*GLDK], Bl[GBN*GLDK];
  const int tid = threadIdx.x;
  const int bm = blockIdx.x, bn = blockIdx.y;
  const int wid = tid >> 6, lane = tid & 63;
  const int wr = wid >> 1, wc = wid & 1;          // 2x2 wave grid, 64x64 each
  const int l15 = lane & 15, lk = (lane >> 4) << 3;

  // staging maps: thread -> row tid>>1 (0..127), k-half (tid&1)*16 (16 shorts)
  const int srow = tid >> 1, sk = (tid & 1) << 4;
  const int agrow = bm*GBM + srow;
  const int asrc = rowmap ? rowmap[agrow] : agrow;
  const unsigned short* ArH = Ahp + (size_t)asrc * Kd + sk;
  const unsigned short* ArL = Alp + (size_t)asrc * Kd + sk;
  const int wrow = bn*GBN + srow;
  const bool bok = (wrow < Nn);
  const unsigned short* BrH = Bhp + (size_t)(bok ? wrow : 0) * Kd + sk;
  const unsigned short* BrL = Blp + (size_t)(bok ? wrow : 0) * Kd + sk;

  f32x4 acc[4][4];
#pragma unroll
  for (int m = 0; m < 4; ++m)
#pragma unroll
    for (int n = 0; n < 4; ++n) acc[m][n] = (f32x4){0.f,0.f,0.f,0.f};

  const uint4 z4 = make_uint4(0u,0u,0u,0u);
  for (int k0 = 0; k0 < Kd; k0 += GBK) {
    const int so = srow*GLDK + sk;
    *(uint4*)&Ah[so]     = *(const uint4*)(ArH + k0);
    *(uint4*)&Ah[so + 8] = *(const uint4*)(ArH + k0 + 8);
    *(uint4*)&Al[so]     = *(const uint4*)(ArL + k0);
    *(uint4*)&Al[so + 8] = *(const uint4*)(ArL + k0 + 8);
    *(uint4*)&Bh[so]     = bok ? *(const uint4*)(BrH + k0)     : z4;
    *(uint4*)&Bh[so + 8] = bok ? *(const uint4*)(BrH + k0 + 8) : z4;
    *(uint4*)&Bl[so]     = bok ? *(const uint4*)(BrL + k0)     : z4;
    *(uint4*)&Bl[so + 8] = bok ? *(const uint4*)(BrL + k0 + 8) : z4;
    __syncthreads();
    bf16x8 afh[4], afl[4], bfh[4], bfl[4];
#pragma unroll
    for (int m = 0; m < 4; ++m) {
      const int row = wr*64 + m*16 + l15;
      afh[m] = *(const bf16x8*)&Ah[row*GLDK + lk];
      afl[m] = *(const bf16x8*)&Al[row*GLDK + lk];
    }
#pragma unroll
    for (int n = 0; n < 4; ++n) {
      const int row = wc*64 + n*16 + l15;
      bfh[n] = *(const bf16x8*)&Bh[row*GLDK + lk];
      bfl[n] = *(const bf16x8*)&Bl[row*GLDK + lk];
    }
#pragma unroll
    for (int m = 0; m < 4; ++m)
#pragma unroll
      for (int n = 0; n < 4; ++n) {
        acc[m][n] = __builtin_amdgcn_mfma_f32_16x16x32_bf16(afh[m], bfh[n], acc[m][n], 0,0,0);
        acc[m][n] = __builtin_amdgcn_mfma_f32_16x16x32_bf16(afh[m], bfl[n], acc[m][n], 0,0,0);
        acc[m][n] = __builtin_amdgcn_mfma_f32_16x16x32_bf16(afl[m], bfh[n], acc[m][n], 0,0,0);
      }
    __syncthreads();
  }
  // epilogue: D col = lane&15, row = (lane>>4)*4 + r
  const int crow0 = bm*GBM + wr*64 + (lane >> 4)*4;
#pragma unroll
  for (int m = 0; m < 4; ++m) {
#pragma unroll
    for (int n = 0; n < 4; ++n) {
      const int col = bn*GBN + wc*64 + n*16 + l15;
      if (col < Nn) {
#pragma unroll
        for (int r = 0; r < 4; ++r) {
          float v = acc[m][n][r];
          if (bias) v += bias[col];
          if (act == 1) v = 0.5f*v*(1.f + erff(v*0.7071067811865475f));
          const size_t idx = (size_t)(crow0 + m*16 + r)*Nn + col;
          if (Yh) {
            const unsigned short h = f2bf(v);
            Yh[idx] = h; Yl[idx] = f2bf(v - bf2f(h));
          } else {
            Y[idx] = v;
          }
        }
      }
    }
  }
}

// -------------------------- kw softmax + neighbor mixing → WB planes -------
__global__ __launch_bounds__(256) void kwmix_kernel(
    const float* __restrict__ QP, const float* __restrict__ wk,
    const float* __restrict__ wb, const float* __restrict__ V,
    unsigned short* __restrict__ Wh, unsigned short* __restrict__ Wl)
{
  const int wave = threadIdx.x >> 6, lane = threadIdx.x & 63;
  const int q = blockIdx.x*4 + wave;
  float qv[4];
#pragma unroll
  for (int j = 0; j < 4; ++j) qv[j] = QP[(size_t)q*256 + lane + 64*j];
  float logit[8];
#pragma unroll
  for (int k = 0; k < 8; ++k) {
    float p = 0.f;
#pragma unroll
    for (int j = 0; j < 4; ++j) p += qv[j]*wk[k*256 + lane + 64*j];
    for (int off = 32; off; off >>= 1) p += __shfl_xor(p, off);
    logit[k] = p + wb[k];
  }
  float mx = logit[0];
#pragma unroll
  for (int k = 1; k < 8; ++k) mx = fmaxf(mx, logit[k]);
  float e[8]; float s = 0.f;
#pragma unroll
  for (int k = 0; k < 8; ++k) { e[k] = expf(logit[k]-mx); s += e[k]; }
  float inv = 1.f/s;
  float acc[4] = {0.f,0.f,0.f,0.f};
#pragma unroll
  for (int k = 0; k < 8; ++k) {
    float kwv = e[k]*inv;
#pragma unroll
    for (int j = 0; j < 4; ++j)
      acc[j] = fmaf(kwv, V[(size_t)(q*8+k)*256 + lane + 64*j], acc[j]);
  }
#pragma unroll
  for (int j = 0; j < 4; ++j) {
    const float v = qv[j]*acc[j];
    const unsigned short h = f2bf(v);
    const size_t o = (size_t)q*256 + lane + 64*j;
    Wh[o] = h; Wl[o] = f2bf(v - bf2f(h));
  }
}

// -------------------------- LayerNorm (fp32 out and/or bf16 planes) --------
__global__ __launch_bounds__(256) void ln_kernel(
    const float* __restrict__ a, const float* __restrict__ b,
    float* __restrict__ out,
    unsigned short* __restrict__ oh, unsigned short* __restrict__ ol,
    int rows)
{
  const int wave = threadIdx.x >> 6, lane = threadIdx.x & 63;
  const int row = blockIdx.x*4 + wave;
  if (row >= rows) return;
  float v[4];
#pragma unroll
  for (int j = 0; j < 4; ++j) {
    float x = a[(size_t)row*256 + lane + 64*j];
    if (b) x += b[(size_t)row*256 + lane + 64*j];
    v[j] = x;
  }
  float s = v[0]+v[1]+v[2]+v[3];
  for (int off = 32; off; off >>= 1) s += __shfl_xor(s, off);
  float m = s * (1.0f/256.0f);
  float t = 0.f;
#pragma unroll
  for (int j = 0; j < 4; ++j) { float d = v[j]-m; t += d*d; }
  for (int off = 32; off; off >>= 1) t += __shfl_xor(t, off);
  float r = rsqrtf(t * (1.0f/256.0f) + 1e-5f);
#pragma unroll
  for (int j = 0; j < 4; ++j) {
    const float y = (v[j]-m)*r;
    const size_t o = (size_t)row*256 + lane + 64*j;
    if (out) out[o] = y;
    if (oh) { const unsigned short h = f2bf(y); oh[o] = h; ol[o] = f2bf(y - bf2f(h)); }
  }
}

// unsort both paths + residual + LN (in-place on X, optional planes)
__global__ __launch_bounds__(256) void ln_unsort_kernel(
    const float* __restrict__ OUTL, const int* __restrict__ INV,
    float* __restrict__ X,
    unsigned short* __restrict__ oh, unsigned short* __restrict__ ol)
{
  const int wave = threadIdx.x >> 6, lane = threadIdx.x & 63;
  const int q = blockIdx.x*4 + wave;
  const int i0 = INV[q], i1 = INV[2048 + q];
  float v[4];
#pragma unroll
  for (int j = 0; j < 4; ++j) {
    int d = lane + 64*j;
    v[j] = X[(size_t)q*256 + d]
         + 0.5f*(OUTL[(size_t)i0*256 + d] + OUTL[(size_t)(2048+i1)*256 + d]);
  }
  float s = v[0]+v[1]+v[2]+v[3];
  for (int off = 32; off; off >>= 1) s += __shfl_xor(s, off);
  float m = s * (1.0f/256.0f);
  float t = 0.f;
#pragma unroll
  for (int j = 0; j < 4; ++j) { float d = v[j]-m; t += d*d; }
  for (int off = 32; off; off >>= 1) t += __shfl_xor(t, off);
  float r = rsqrtf(t * (1.0f/256.0f) + 1e-5f);
#pragma unroll
  for (int j = 0; j < 4; ++j) {
    const float y = (v[j]-m)*r;
    const size_t o = (size_t)q*256 + lane + 64*j;
    X[o] = y;
    if (oh) { const unsigned short h = f2bf(y); oh[o] = h; ol[o] = f2bf(y - bf2f(h)); }
  }
}

// -------------------------- causal depthwise conv (KC=4) + SiLU ------------
__global__ void conv_kernel(const float* __restrict__ PROJ,
    const float* __restrict__ Wc, const float* __restrict__ bc,
    float* __restrict__ XBC)
{
  const int c = threadIdx.x;      // 640
  const int bt = blockIdx.x;      // 4096
  const int t = bt & 2047;
  float acc = bc[c];
#pragma unroll
  for (int j = 0; j < 4; ++j) {
    int d = j - 3;
    if (t + d >= 0)
      acc = fmaf(PROJ[(size_t)(bt + d)*1160 + 512 + c], Wc[c*4+j], acc);
  }
  XBC[(size_t)bt*640 + c] = acc / (1.f + expf(-acc));  // silu
}

// -------------------------- dt softplus + dA -------------------------------
__global__ void dta_kernel(const float* __restrict__ PROJ,
    const float* __restrict__ dtb, const float* __restrict__ Alog,
    float* __restrict__ Ddt, float* __restrict__ Dda)
{
  const int i = blockIdx.x*256 + threadIdx.x;   // 32768 = 4096*8
  const int bt = i >> 3, hh = i & 7;
  float x = PROJ[(size_t)bt*1160 + 1152 + hh] + dtb[hh];
  float dt = (x > 20.f) ? x : log1pf(expf(x));
  float A = -expf(Alog[hh]);
  Ddt[hh*4096 + bt] = dt;
  Dda[hh*4096 + bt] = expf(dt * A);
}

// -------------------------- scan pass 1: per-chunk S_c, P_c ----------------
__global__ __launch_bounds__(64) void scan1_kernel(
    const float* __restrict__ XBC, const float* __restrict__ Ddt,
    const float* __restrict__ Dda, float* __restrict__ SCH, float* __restrict__ PC)
{
  const int blk = blockIdx.x;
  const int c = blk & 31, hh = (blk >> 5) & 7, b = blk >> 8;
  const int lane = threadIdx.x;
  const int t0 = (b << 11) + (c << 6);
  __shared__ float Bsh[64][64];
  __shared__ float Xsh[64][64];
  __shared__ float dAs[64], dts[64];
#pragma unroll
  for (int it = 0; it < 16; ++it) {
    int idx = it*64 + lane;
    int t = idx >> 4, c4 = (idx & 15) << 2;
    *(float4*)&Bsh[t][c4] = *(const float4*)&XBC[(size_t)(t0 + t)*640 + 512 + c4];
    *(float4*)&Xsh[t][c4] = *(const float4*)&XBC[(size_t)(t0 + t)*640 + (hh<<6) + c4];
  }
  dAs[lane] = Dda[hh*4096 + t0 + lane];
  dts[lane] = Ddt[hh*4096 + t0 + lane];
  __syncthreads();
  float h[64];
#pragma unroll
  for (int s = 0; s < 64; ++s) h[s] = 0.f;
  float p = 1.f;
  for (int t = 0; t < 64; ++t) {
    const float dA = dAs[t];
    const float u = dts[t]*Xsh[t][lane];
    p *= dA;
    const float4* B4 = (const float4*)&Bsh[t][0];
#pragma unroll
    for (int s4 = 0; s4 < 16; ++s4) {
      float4 bv = B4[s4];
      h[4*s4+0] = fmaf(h[4*s4+0], dA, bv.x*u);
      h[4*s4+1] = fmaf(h[4*s4+1], dA, bv.y*u);
      h[4*s4+2] = fmaf(h[4*s4+2], dA, bv.z*u);
      h[4*s4+3] = fmaf(h[4*s4+3], dA, bv.w*u);
    }
  }
  float* op = SCH + (size_t)blk*4096 + lane*64;
#pragma unroll
  for (int s4 = 0; s4 < 16; ++s4)
    ((float4*)op)[s4] = make_float4(h[4*s4], h[4*s4+1], h[4*s4+2], h[4*s4+3]);
  if (lane == 0) PC[blk] = p;
}

// -------------------------- sequential cross-chunk combine (in-place) ------
__global__ void combine_kernel(float* __restrict__ SCH, const float* __restrict__ PC)
{
  const int tid = blockIdx.x*256 + threadIdx.x;   // 65536
  const int bh = tid >> 12, ds = tid & 4095;
  float h = 0.f;
  for (int cc = 0; cc < 32; ++cc) {
    size_t o = ((size_t)(bh*32 + cc) << 12) + ds;
    float s = SCH[o];
    SCH[o] = h;
    h = fmaf(h, PC[bh*32+cc], s);
  }
}

// -------------------------- scan pass 2: exact recurrence + y --------------
__global__ __launch_bounds__(64) void scan2_kernel(
    const float* __restrict__ XBC, const float* __restrict__ Ddt,
    const float* __restrict__ Dda, const float* __restrict__ HST,
    const float* __restrict__ Dm, float* __restrict__ Yout)
{
  const int blk = blockIdx.x;
  const int c = blk & 31, hh = (blk >> 5) & 7, b = blk >> 8;
  const int lane = threadIdx.x;
  const int t0 = (b << 11) + (c << 6);
  __shared__ float Bsh[64][64];
  __shared__ float Csh[64][64];
  __shared__ float Xsh[64][64];
  __shared__ float dAs[64], dts[64];
#pragma unroll
  for (int it = 0; it < 16; ++it) {
    int idx = it*64 + lane;
    int t = idx >> 4, c4 = (idx & 15) << 2;
    *(float4*)&Bsh[t][c4] = *(const float4*)&XBC[(size_t)(t0 + t)*640 + 512 + c4];
    *(float4*)&Csh[t][c4] = *(const float4*)&XBC[(size_t)(t0 + t)*640 + 576 + c4];
    *(float4*)&Xsh[t][c4] = *(const float4*)&XBC[(size_t)(t0 + t)*640 + (hh<<6) + c4];
  }
  dAs[lane] = Dda[hh*4096 + t0 + lane];
  dts[lane] = Ddt[hh*4096 + t0 + lane];
  const float Dh = Dm[hh];
  float h[64];
  const float4* hp = (const float4*)(HST + (size_t)blk*4096 + lane*64);
#pragma unroll
  for (int s4 = 0; s4 < 16; ++s4) {
    float4 t4 = hp[s4];
    h[4*s4+0]=t4.x; h[4*s4+1]=t4.y; h[4*s4+2]=t4.z; h[4*s4+3]=t4.w;
  }
  __syncthreads();
  for (int t = 0; t < 64; ++t) {
    const float dA = dAs[t];
    const float u = dts[t]*Xsh[t][lane];
    float y = 0.f;
    const float4* B4 = (const float4*)&Bsh[t][0];
    const float4* C4 = (const float4*)&Csh[t][0];
#pragma unroll
    for (int s4 = 0; s4 < 16; ++s4) {
      float4 bv = B4[s4];
      float4 cv = C4[s4];
      h[4*s4+0] = fmaf(h[4*s4+0], dA, bv.x*u); y = fmaf(cv.x, h[4*s4+0], y);
      h[4*s4+1] = fmaf(h[4*s4+1], dA, bv.y*u); y = fmaf(cv.y, h[4*s4+1], y);
      h[4*s4+2] = fmaf(h[4*s4+2], dA, bv.z*u); y = fmaf(cv.z, h[4*s4+2], y);
      h[4*s4+3] = fmaf(h[4*s4+3], dA, bv.w*u); y = fmaf(cv.w, h[4*s4+3], y);
    }
    Yout[(size_t)(t0 + t)*512 + (hh<<6) + lane] = y + Dh*Xsh[t][lane];
  }
}

// -------------- gate (silu(z)) + RMSNorm over 512 → Yb bf16 planes ---------
__global__ __launch_bounds__(256) void gaterms_kernel(
    const float* __restrict__ Y, const float* __restrict__ PROJ,
    const float* __restrict__ rmsw,
    unsigned short* __restrict__ Oh, unsigned short* __restrict__ Ol)
{
  const int wave = threadIdx.x >> 6, lane = threadIdx.x & 63;
  const int row = blockIdx.x*4 + wave;   // 4096
  float v[8]; float ss = 0.f;
#pragma unroll
  for (int j = 0; j < 8; ++j) {
    float y = Y[(size_t)row*512 + lane + 64*j];
    float z = PROJ[(size_t)row*1160 + lane + 64*j];
    float g = y * (z / (1.f + expf(-z)));
    v[j] = g; ss += g*g;
  }
  for (int off = 32; off; off >>= 1) ss += __shfl_xor(ss, off);
  float r = rsqrtf(ss * (1.0f/512.0f) + 1e-5f);
#pragma unroll
  for (int j = 0; j < 8; ++j) {
    const float o = v[j] * r * rmsw[lane + 64*j];
    const unsigned short h = f2bf(o);
    const size_t ix = (size_t)row*512 + lane + 64*j;
    Oh[ix] = h; Ol[ix] = f2bf(o - bf2f(h));
  }
}

// ---------------------------------------------------------------------------
extern "C" void kernel_launch(void* const* d_in, const int* in_sizes, int n_in,
                              void* d_out, int out_size, void* d_ws, size_t ws_size,
                              hipStream_t stream)
{
  (void)in_sizes; (void)n_in; (void)out_size; (void)ws_size;
  const float* query = (const float*)d_in[0];
  const float* qpos  = (const float*)d_in[1];
  const float* feats = (const float*)d_in[2];
  const float* spos  = (const float*)d_in[3];
  const float* w_q   = (const float*)d_in[4];
  const float* w_v   = (const float*)d_in[5];
  const float* w_o   = (const float*)d_in[6];
  const float* w_k   = (const float*)d_in[7];
  const float* w_b   = (const float*)d_in[8];
  const float* Win   = (const float*)d_in[9];
  const float* Wconv = (const float*)d_in[10];
  const float* bconv = (const float*)d_in[11];
  const float* Alog  = (const float*)d_in[12];
  const float* Dm    = (const float*)d_in[13];
  const float* dtb   = (const float*)d_in[14];
  const float* rmsw  = (const float*)d_in[15];
  const float* Wout  = (const float*)d_in[16];
  const float* fw1   = (const float*)d_in[17];
  const float* fb1   = (const float*)d_in[18];
  const float* fw2   = (const float*)d_in[19];
  const float* fb2   = (const float*)d_in[20];
  const int*   order = (const int*)d_in[21];
  float* out = (float*)d_out;

  char* ws = (char*)d_ws;
  size_t off = 0;
  auto alloc = [&](size_t bytes) -> void* {
    void* p = ws + off;
    off = (off + bytes + 255) & ~(size_t)255;
    return p;
  };
  int*   IDX = (int*)alloc((size_t)2048*8*4);
  int*   INV = (int*)alloc((size_t)4096*4);
  float* PC  = (float*)alloc((size_t)512*4);
  float4* P4 = (float4*)alloc((size_t)32768*16);
  float* Ddt = (float*)alloc((size_t)4096*8*4);
  float* Dda = (float*)alloc((size_t)4096*8*4);
  float* QP  = (float*)alloc((size_t)2048*256*4);
  float* WO  = (float*)alloc((size_t)2048*256*4);
  float* X   = (float*)alloc((size_t)2048*256*4);
  float* U1  = (float*)alloc((size_t)4096*1160*4);  // V (16MB) | PROJ (19MB)
  float* U2  = (float*)alloc((size_t)4096*640*4);   // XBC
  float* SCH = (float*)alloc((size_t)512*4096*4);   // chunk states
  float* Yb  = (float*)alloc((size_t)4096*512*4);
  float* U6  = (float*)alloc((size_t)4096*256*4);   // OUTL | FFO
  // bf16 split planes
  unsigned short* Qh  = (unsigned short*)alloc((size_t)2048*256*2);
  unsigned short* Ql  = (unsigned short*)alloc((size_t)2048*256*2);
  unsigned short* U7h = (unsigned short*)alloc((size_t)32768*256*2); // feats | FFH planes
  unsigned short* U7l = (unsigned short*)alloc((size_t)32768*256*2);
  unsigned short* WBh = (unsigned short*)alloc((size_t)2048*256*2);
  unsigned short* WBl = (unsigned short*)alloc((size_t)2048*256*2);
  unsigned short* XNh = (unsigned short*)alloc((size_t)2048*256*2);
  unsigned short* XNl = (unsigned short*)alloc((size_t)2048*256*2);
  unsigned short* Ybh = (unsigned short*)alloc((size_t)4096*512*2);
  unsigned short* Ybl = (unsigned short*)alloc((size_t)4096*512*2);
  unsigned short* Xh  = (unsigned short*)alloc((size_t)2048*256*2);
  unsigned short* Xl  = (unsigned short*)alloc((size_t)2048*256*2);
  unsigned short* Wqh = (unsigned short*)alloc((size_t)256*256*2);
  unsigned short* Wql = (unsigned short*)alloc((size_t)256*256*2);
  unsigned short* Wvh = (unsigned short*)alloc((size_t)256*256*2);
  unsigned short* Wvl = (unsigned short*)alloc((size_t)256*256*2);
  unsigned short* Woh = (unsigned short*)alloc((size_t)256*256*2);
  unsigned short* Wol = (unsigned short*)alloc((size_t)256*256*2);
  unsigned short* Wih = (unsigned short*)alloc((size_t)2*1160*256*2);
  unsigned short* Wil = (unsigned short*)alloc((size_t)2*1160*256*2);
  unsigned short* Wuh = (unsigned short*)alloc((size_t)2*256*512*2);
  unsigned short* Wul = (unsigned short*)alloc((size_t)2*256*512*2);
  unsigned short* F1h = (unsigned short*)alloc((size_t)1024*256*2);
  unsigned short* F1l = (unsigned short*)alloc((size_t)1024*256*2);
  unsigned short* F2h = (unsigned short*)alloc((size_t)256*1024*2);
  unsigned short* F2l = (unsigned short*)alloc((size_t)256*1024*2);
  float* Vb   = U1;  float* PROJ = U1;
  float* XBC  = U2;
  float* OUTL = U6;  float* FFO  = U6;
  unsigned short* FFHh = U7h;  // feats planes dead after stage 1
  unsigned short* FFHl = U7l;

  auto cvt = [&](const float* s, unsigned short* h, unsigned short* l, int n) {
    cvt_kernel<<<(n/4 + 255)/256, 256, 0, stream>>>(s, h, l, n/4);
  };

  // --- stage 1: KNN + aggregation ---
  inv_kernel<<<16, 256, 0, stream>>>(order, INV);
  prep_kernel<<<128, 256, 0, stream>>>(spos, P4);
  knn_kernel<<<2048, 256, 0, stream>>>(qpos, P4, IDX);
  cvt(query, Qh, Ql, 2048*256);
  cvt(feats, U7h, U7l, 32768*256);
  cvt(w_q, Wqh, Wql, 256*256);
  cvt(w_v, Wvh, Wvl, 256*256);
  cvt(w_o, Woh, Wol, 256*256);
  cvt(Win, Wih, Wil, 2*1160*256);
  cvt(Wout, Wuh, Wul, 2*256*512);
  cvt(fw1, F1h, F1l, 1024*256);
  cvt(fw2, F2h, F2l, 256*1024);
  gemm_mfma<<<dim3(16,2), 256, 0, stream>>>(Qh, Ql, nullptr, Wqh, Wql, nullptr,
                                            QP, nullptr, nullptr, 2048,256,256,0);
  gemm_mfma<<<dim3(128,2), 256, 0, stream>>>(U7h, U7l, IDX, Wvh, Wvl, nullptr,
                                             Vb, nullptr, nullptr, 16384,256,256,0);
  kwmix_kernel<<<512, 256, 0, stream>>>(QP, w_k, w_b, Vb, WBh, WBl);
  gemm_mfma<<<dim3(16,2), 256, 0, stream>>>(WBh, WBl, nullptr, Woh, Wol, nullptr,
                                            WO, nullptr, nullptr, 2048,256,256,0);
  ln_kernel<<<512, 256, 0, stream>>>(WO, query, X, nullptr, nullptr, 2048);

  // --- stage 2: two Mamba2 layers ---
  for (int l = 0; l < 2; ++l) {
    ln_kernel<<<512, 256, 0, stream>>>(X, nullptr, nullptr, XNh, XNl, 2048);
    gemm_mfma<<<dim3(32,10), 256, 0, stream>>>(XNh, XNl, order,
                                               Wih + (size_t)l*1160*256,
                                               Wil + (size_t)l*1160*256,
                                               nullptr, PROJ, nullptr, nullptr,
                                               4096,1160,256,0);
    conv_kernel<<<4096, 640, 0, stream>>>(PROJ, Wconv + l*640*4, bconv + l*640, XBC);
    dta_kernel<<<128, 256, 0, stream>>>(PROJ, dtb + l*8, Alog + l*8, Ddt, Dda);
    scan1_kernel<<<512, 64, 0, stream>>>(XBC, Ddt, Dda, SCH, PC);
    combine_kernel<<<256, 256, 0, stream>>>(SCH, PC);
    scan2_kernel<<<512, 64, 0, stream>>>(XBC, Ddt, Dda, SCH, Dm + l*8, Yb);
    gaterms_kernel<<<1024, 256, 0, stream>>>(Yb, PROJ, rmsw + l*512, Ybh, Ybl);
    gemm_mfma<<<dim3(32,2), 256, 0, stream>>>(Ybh, Ybl, nullptr,
                                              Wuh + (size_t)l*256*512,
                                              Wul + (size_t)l*256*512,
                                              nullptr, OUTL, nullptr, nullptr,
                                              4096,256,512,0);
    ln_unsort_kernel<<<512, 256, 0, stream>>>(OUTL, INV, X,
                                              (l==1) ? Xh : nullptr,
                                              (l==1) ? Xl : nullptr);
  }

  // --- stage 3: FFN ---
  gemm_mfma<<<dim3(16,8), 256, 0, stream>>>(Xh, Xl, nullptr, F1h, F1l, fb1,
                                            nullptr, FFHh, FFHl, 2048,1024,256,1);
  gemm_mfma<<<dim3(16,2), 256, 0, stream>>>(FFHh, FFHl, nullptr, F2h, F2l, fb2,
                                            FFO, nullptr, nullptr, 2048,256,1024,0);
  ln_kernel<<<512, 256, 0, stream>>>(FFO, X, out, nullptr, nullptr, 2048);
}

// Round 11
// 583.994 us; speedup vs baseline: 1.1283x; 1.1283x over previous
//
#include <hip/hip_runtime.h>
#include <cstdint>

// ---------------------------------------------------------------------------
// LaSSMDecoder on MI355X — Round 11:
//  (a) GEMM tile reverted to 128x64 (round-10's 128x128 cost +75 µs: small
//      grids at K=256 expose barrier drain; guide: 128² for 2-barrier loops).
//  (b) KNN kept from round 10 (85 µs: float keys, pointer-increment).
//  (c) NEW: neighbor mixing factored through linearity —
//      sum_k kw_k (feat_k @ Wv^T) == (sum_k kw_k feat_k) @ Wv^T.
//      kwmix2 mixes gathered fp32 feats -> F planes; one 2048-row GEMM with
//      fused ⊙QP epilogue -> WB planes. 8x fewer V-path FLOPs, no feats cvt.
// ---------------------------------------------------------------------------

typedef __attribute__((ext_vector_type(8))) short bf16x8;
typedef __attribute__((ext_vector_type(4))) float f32x4;

__device__ __forceinline__ unsigned short f2bf(float f) {
  unsigned int u = __float_as_uint(f);
  u += 0x7fff + ((u >> 16) & 1);        // RNE
  return (unsigned short)(u >> 16);
}
__device__ __forceinline__ float bf2f(unsigned short h) {
  return __uint_as_float(((unsigned int)h) << 16);
}

// -------------------------- fp32 -> (hi, lo) bf16 planes -------------------
__global__ __launch_bounds__(256) void cvt_kernel(
    const float* __restrict__ src, unsigned short* __restrict__ hi,
    unsigned short* __restrict__ lo, int n4)
{
  const int i = blockIdx.x*256 + threadIdx.x;
  if (i < n4) {
    const float4 v = ((const float4*)src)[i];
    const unsigned short h0=f2bf(v.x), h1=f2bf(v.y), h2=f2bf(v.z), h3=f2bf(v.w);
    const unsigned short l0=f2bf(v.x-bf2f(h0)), l1=f2bf(v.y-bf2f(h1)),
                         l2=f2bf(v.z-bf2f(h2)), l3=f2bf(v.w-bf2f(h3));
    ((uint2*)hi)[i] = make_uint2((unsigned)h0 | ((unsigned)h1<<16),
                                 (unsigned)h2 | ((unsigned)h3<<16));
    ((uint2*)lo)[i] = make_uint2((unsigned)l0 | ((unsigned)l1<<16),
                                 (unsigned)l2 | ((unsigned)l3<<16));
  }
}

// ---------------- wave-uniform top-8 list in named registers (float keys) --
__device__ __forceinline__ bool flex_less(float d, int i, float dr, int ir) {
  return d < dr || (d == dr && i < ir);
}

#define KNN_INS_F(dv, iv)                                                      \
  do {                                                                         \
    const float _d = (dv); const int _v = (iv);                                \
    const bool a0 = _d < bd0;                                                  \
    const bool a1 = _d < bd1;                                                  \
    const bool a2 = _d < bd2;                                                  \
    const bool a3 = _d < bd3;                                                  \
    const bool a4 = _d < bd4;                                                  \
    const bool a5 = _d < bd5;                                                  \
    const bool a6 = _d < bd6;                                                  \
    bd7 = a6 ? bd6 : _d;              id7 = a6 ? id6 : _v;                     \
    bd6 = a5 ? bd5 : (a6 ? _d : bd6); id6 = a5 ? id5 : (a6 ? _v : id6);        \
    bd5 = a4 ? bd4 : (a5 ? _d : bd5); id5 = a4 ? id4 : (a5 ? _v : id5);        \
    bd4 = a3 ? bd3 : (a4 ? _d : bd4); id4 = a3 ? id3 : (a4 ? _v : id4);        \
    bd3 = a2 ? bd2 : (a3 ? _d : bd3); id3 = a2 ? id2 : (a3 ? _v : id3);        \
    bd2 = a1 ? bd1 : (a2 ? _d : bd2); id2 = a1 ? id1 : (a2 ? _v : id2);        \
    bd1 = a0 ? bd0 : (a1 ? _d : bd1); id1 = a0 ? id0 : (a1 ? _v : id1);        \
    bd0 = a0 ? _d : bd0;              id0 = a0 ? _v : id0;                     \
  } while (0)

#define KNN_INS_FLEX(dv, iv)                                                   \
  do {                                                                         \
    const float _d = (dv); const int _v = (iv);                                \
    const bool a0 = flex_less(_d, _v, bd0, id0);                               \
    const bool a1 = flex_less(_d, _v, bd1, id1);                               \
    const bool a2 = flex_less(_d, _v, bd2, id2);                               \
    const bool a3 = flex_less(_d, _v, bd3, id3);                               \
    const bool a4 = flex_less(_d, _v, bd4, id4);                               \
    const bool a5 = flex_less(_d, _v, bd5, id5);                               \
    const bool a6 = flex_less(_d, _v, bd6, id6);                               \
    bd7 = a6 ? bd6 : _d;              id7 = a6 ? id6 : _v;                     \
    bd6 = a5 ? bd5 : (a6 ? _d : bd6); id6 = a5 ? id5 : (a6 ? _v : id6);        \
    bd5 = a4 ? bd4 : (a5 ? _d : bd5); id5 = a4 ? id4 : (a5 ? _v : id5);        \
    bd4 = a3 ? bd3 : (a4 ? _d : bd4); id4 = a3 ? id3 : (a4 ? _v : id4);        \
    bd3 = a2 ? bd2 : (a3 ? _d : bd3); id3 = a2 ? id2 : (a3 ? _v : id3);        \
    bd2 = a1 ? bd1 : (a2 ? _d : bd2); id2 = a1 ? id1 : (a2 ? _v : id2);        \
    bd1 = a0 ? bd0 : (a1 ? _d : bd1); id1 = a0 ? id0 : (a1 ? _v : id1);        \
    bd0 = a0 ? _d : bd0;              id0 = a0 ? _v : id0;                     \
  } while (0)

#define KNN_RESET_F()                                                          \
  do {                                                                         \
    bd0=bd1=bd2=bd3=bd4=bd5=bd6=bd7 = 3.4e38f;                                 \
    id0=id1=id2=id3=id4=id5=id6=id7 = 0x7fffffff;                              \
  } while (0)

// -------------------------- prep: pack (sx,sy,sz,|s|^2) as float4 ----------
__global__ void prep_kernel(const float* __restrict__ spos,
                            float4* __restrict__ P4)
{
#pragma clang fp contract(off)
  const int n = blockIdx.x*256 + threadIdx.x;
  if (n < 32768) {
    const float sx = spos[n*3+0], sy = spos[n*3+1], sz = spos[n*3+2];
    P4[n] = make_float4(sx, sy, sz, sx*sx + sy*sy + sz*sz);
  }
}

// -------------------------- KNN: 1 query / block, 4 waves ------------------
__global__ __launch_bounds__(256) void knn_kernel(
    const float* __restrict__ qpos, const float4* __restrict__ P4,
    int* __restrict__ idx_out)
{
#pragma clang fp contract(off)
  __shared__ float skey[32];
  __shared__ int   sidx[32];
  const int q = blockIdx.x, tid = threadIdx.x;
  const int wave = tid >> 6, lane = tid & 63;
  const float qx = qpos[q*3+0], qy = qpos[q*3+1], qz = qpos[q*3+2];
  const float qq = qx*qx + qy*qy + qz*qz;
  float bd0,bd1,bd2,bd3,bd4,bd5,bd6,bd7;
  int   id0,id1,id2,id3,id4,id5,id6,id7;
  KNN_RESET_F();
  const float4* pp = P4 + (wave << 13) + lane;   // 8192 pts per wave
  int nb = (wave << 13);
  for (int it = 0; it < 128; ++it) {
    const float4 p = *pp;  pp += 64;
    const float d2 = (qq + p.w) - 2.0f*(qx*p.x + qy*p.y + qz*p.z);  // exact ref formula
    unsigned long long m = __ballot(d2 < bd7);
    while (m) {
      const int l = __ffsll(m) - 1;
      m &= m - 1;
      const float dk = __shfl(d2, l);
      if (dk < bd7) KNN_INS_F(dk, nb + l);
    }
    nb += 64;
  }
  if (lane == 0) {
    const int o = wave*8;
    skey[o+0]=bd0; skey[o+1]=bd1; skey[o+2]=bd2; skey[o+3]=bd3;
    skey[o+4]=bd4; skey[o+5]=bd5; skey[o+6]=bd6; skey[o+7]=bd7;
    sidx[o+0]=id0; sidx[o+1]=id1; sidx[o+2]=id2; sidx[o+3]=id3;
    sidx[o+4]=id4; sidx[o+5]=id5; sidx[o+6]=id6; sidx[o+7]=id7;
  }
  __syncthreads();
  if (tid == 0) {
    KNN_RESET_F();
    for (int s = 0; s < 32; ++s) {
      const float dk = skey[s];
      const int   ui = sidx[s];
      if (flex_less(dk, ui, bd7, id7)) KNN_INS_FLEX(dk, ui);
    }
    idx_out[q*8+0]=id0; idx_out[q*8+1]=id1; idx_out[q*8+2]=id2; idx_out[q*8+3]=id3;
    idx_out[q*8+4]=id4; idx_out[q*8+5]=id5; idx_out[q*8+6]=id6; idx_out[q*8+7]=id7;
  }
}

// -------------------------- inverse permutation ----------------------------
__global__ void inv_kernel(const int* __restrict__ order, int* __restrict__ inv)
{
  int i = blockIdx.x*blockDim.x + threadIdx.x;
  if (i < 4096) { int b = i >> 11, t = i & 2047; inv[(b<<11) + order[i]] = t; }
}

// -------------------------- MFMA GEMM on pre-split bf16 planes -------------
// Y = act(A[rowmap] @ Wt^T + b) [⊙ emul]; optional (Yh,Yl) plane output.
// Tile 128x64, 4 waves (2x2), per-wave 4x2 frags of 16x16x32, BK=32.
#define GBM 128
#define GBN 64
#define GBK 32
#define GLDK 40   // padded LDS row length (bf16 units): 32 + 8
__global__ __launch_bounds__(256) void gemm_mfma(
    const unsigned short* __restrict__ Ahp, const unsigned short* __restrict__ Alp,
    const int* __restrict__ rowmap,
    const unsigned short* __restrict__ Bhp, const unsigned short* __restrict__ Blp,
    const float* __restrict__ bias, const float* __restrict__ emul,
    float* __restrict__ Y,
    unsigned short* __restrict__ Yh, unsigned short* __restrict__ Yl,
    int M, int Nn, int Kd, int act)
{
  __shared__ unsigned short Ah[GBM*GLDK], Al[GBM*GLDK];
  __shared__ unsigned short Bh[GBN*GLDK], Bl[GBN*GLDK];
  const int tid = threadIdx.x;
  const int bm = blockIdx.x, bn = blockIdx.y;
  const int wid = tid >> 6, lane = tid & 63;
  const int wr = wid >> 1, wc = wid & 1;          // 2x2 wave grid
  const int l15 = lane & 15, lk = (lane >> 4) << 3;

  const int sar = tid >> 1, sak = (tid & 1) << 4;
  const int agrow = bm*GBM + sar;
  const int asrc = rowmap ? rowmap[agrow] : agrow;
  const unsigned short* ArH = Ahp + (size_t)asrc * Kd + sak;
  const unsigned short* ArL = Alp + (size_t)asrc * Kd + sak;
  const int sbr = tid >> 2, sbk = (tid & 3) << 3;
  const int wrow = bn*GBN + sbr;
  const bool bok = (wrow < Nn);
  const unsigned short* BrH = Bhp + (size_t)(bok ? wrow : 0) * Kd + sbk;
  const unsigned short* BrL = Blp + (size_t)(bok ? wrow : 0) * Kd + sbk;

  f32x4 acc[4][2];
#pragma unroll
  for (int m = 0; m < 4; ++m)
#pragma unroll
    for (int n = 0; n < 2; ++n) acc[m][n] = (f32x4){0.f,0.f,0.f,0.f};

  const uint4 z4 = make_uint4(0u,0u,0u,0u);
  for (int k0 = 0; k0 < Kd; k0 += GBK) {
    const int ao = sar*GLDK + sak;
    *(uint4*)&Ah[ao]     = *(const uint4*)(ArH + k0);
    *(uint4*)&Ah[ao + 8] = *(const uint4*)(ArH + k0 + 8);
    *(uint4*)&Al[ao]     = *(const uint4*)(ArL + k0);
    *(uint4*)&Al[ao + 8] = *(const uint4*)(ArL + k0 + 8);
    const int bo = sbr*GLDK + sbk;
    *(uint4*)&Bh[bo] = bok ? *(const uint4*)(BrH + k0) : z4;
    *(uint4*)&Bl[bo] = bok ? *(const uint4*)(BrL + k0) : z4;
    __syncthreads();
    bf16x8 afh[4], afl[4], bfh[2], bfl[2];
#pragma unroll
    for (int m = 0; m < 4; ++m) {
      const int row = wr*64 + m*16 + l15;
      afh[m] = *(const bf16x8*)&Ah[row*GLDK + lk];
      afl[m] = *(const bf16x8*)&Al[row*GLDK + lk];
    }
#pragma unroll
    for (int n = 0; n < 2; ++n) {
      const int row = wc*32 + n*16 + l15;
      bfh[n] = *(const bf16x8*)&Bh[row*GLDK + lk];
      bfl[n] = *(const bf16x8*)&Bl[row*GLDK + lk];
    }
#pragma unroll
    for (int m = 0; m < 4; ++m)
#pragma unroll
      for (int n = 0; n < 2; ++n) {
        acc[m][n] = __builtin_amdgcn_mfma_f32_16x16x32_bf16(afh[m], bfh[n], acc[m][n], 0,0,0);
        acc[m][n] = __builtin_amdgcn_mfma_f32_16x16x32_bf16(afh[m], bfl[n], acc[m][n], 0,0,0);
        acc[m][n] = __builtin_amdgcn_mfma_f32_16x16x32_bf16(afl[m], bfh[n], acc[m][n], 0,0,0);
      }
    __syncthreads();
  }
  const int crow0 = bm*GBM + wr*64 + (lane >> 4)*4;
#pragma unroll
  for (int m = 0; m < 4; ++m) {
#pragma unroll
    for (int n = 0; n < 2; ++n) {
      const int col = bn*GBN + wc*32 + n*16 + l15;
      if (col < Nn) {
#pragma unroll
        for (int r = 0; r < 4; ++r) {
          float v = acc[m][n][r];
          if (bias) v += bias[col];
          if (act == 1) v = 0.5f*v*(1.f + erff(v*0.7071067811865475f));
          const size_t idx = (size_t)(crow0 + m*16 + r)*Nn + col;
          if (emul) v *= emul[idx];
          if (Yh) {
            const unsigned short h = f2bf(v);
            Yh[idx] = h; Yl[idx] = f2bf(v - bf2f(h));
          } else {
            Y[idx] = v;
          }
        }
      }
    }
  }
}

// ------------- kw softmax + fp32 feat gather/mix → F planes ----------------
// F[q] = sum_k softmax(QP[q]·w_k + w_b)_k * feats[idx[q,k]]
__global__ __launch_bounds__(256) void kwmix2_kernel(
    const float* __restrict__ QP, const float* __restrict__ wk,
    const float* __restrict__ wb, const float* __restrict__ feats,
    const int* __restrict__ IDX,
    unsigned short* __restrict__ Fh, unsigned short* __restrict__ Fl)
{
  const int wave = threadIdx.x >> 6, lane = threadIdx.x & 63;
  const int q = blockIdx.x*4 + wave;
  float qv[4];
#pragma unroll
  for (int j = 0; j < 4; ++j) qv[j] = QP[(size_t)q*256 + lane + 64*j];
  float logit[8];
#pragma unroll
  for (int k = 0; k < 8; ++k) {
    float p = 0.f;
#pragma unroll
    for (int j = 0; j < 4; ++j) p += qv[j]*wk[k*256 + lane + 64*j];
    for (int off = 32; off; off >>= 1) p += __shfl_xor(p, off);
    logit[k] = p + wb[k];
  }
  float mx = logit[0];
#pragma unroll
  for (int k = 1; k < 8; ++k) mx = fmaxf(mx, logit[k]);
  float e[8]; float s = 0.f;
#pragma unroll
  for (int k = 0; k < 8; ++k) { e[k] = expf(logit[k]-mx); s += e[k]; }
  float inv = 1.f/s;
  float acc[4] = {0.f,0.f,0.f,0.f};
#pragma unroll
  for (int k = 0; k < 8; ++k) {
    const float kwv = e[k]*inv;
    const int ii = IDX[q*8+k];
#pragma unroll
    for (int j = 0; j < 4; ++j)
      acc[j] = fmaf(kwv, feats[(size_t)ii*256 + lane + 64*j], acc[j]);
  }
#pragma unroll
  for (int j = 0; j < 4; ++j) {
    const unsigned short h = f2bf(acc[j]);
    const size_t o = (size_t)q*256 + lane + 64*j;
    Fh[o] = h; Fl[o] = f2bf(acc[j] - bf2f(h));
  }
}

// -------------------------- LayerNorm (fp32 out and/or bf16 planes) --------
__global__ __launch_bounds__(256) void ln_kernel(
    const float* __restrict__ a, const float* __restrict__ b,
    float* __restrict__ out,
    unsigned short* __restrict__ oh, unsigned short* __restrict__ ol,
    int rows)
{
  const int wave = threadIdx.x >> 6, lane = threadIdx.x & 63;
  const int row = blockIdx.x*4 + wave;
  if (row >= rows) return;
  float v[4];
#pragma unroll
  for (int j = 0; j < 4; ++j) {
    float x = a[(size_t)row*256 + lane + 64*j];
    if (b) x += b[(size_t)row*256 + lane + 64*j];
    v[j] = x;
  }
  float s = v[0]+v[1]+v[2]+v[3];
  for (int off = 32; off; off >>= 1) s += __shfl_xor(s, off);
  float m = s * (1.0f/256.0f);
  float t = 0.f;
#pragma unroll
  for (int j = 0; j < 4; ++j) { float d = v[j]-m; t += d*d; }
  for (int off = 32; off; off >>= 1) t += __shfl_xor(t, off);
  float r = rsqrtf(t * (1.0f/256.0f) + 1e-5f);
#pragma unroll
  for (int j = 0; j < 4; ++j) {
    const float y = (v[j]-m)*r;
    const size_t o = (size_t)row*256 + lane + 64*j;
    if (out) out[o] = y;
    if (oh) { const unsigned short h = f2bf(y); oh[o] = h; ol[o] = f2bf(y - bf2f(h)); }
  }
}

// unsort both paths + residual + LN (in-place on X, optional planes)
__global__ __launch_bounds__(256) void ln_unsort_kernel(
    const float* __restrict__ OUTL, const int* __restrict__ INV,
    float* __restrict__ X,
    unsigned short* __restrict__ oh, unsigned short* __restrict__ ol)
{
  const int wave = threadIdx.x >> 6, lane = threadIdx.x & 63;
  const int q = blockIdx.x*4 + wave;
  const int i0 = INV[q], i1 = INV[2048 + q];
  float v[4];
#pragma unroll
  for (int j = 0; j < 4; ++j) {
    int d = lane + 64*j;
    v[j] = X[(size_t)q*256 + d]
         + 0.5f*(OUTL[(size_t)i0*256 + d] + OUTL[(size_t)(2048+i1)*256 + d]);
  }
  float s = v[0]+v[1]+v[2]+v[3];
  for (int off = 32; off; off >>= 1) s += __shfl_xor(s, off);
  float m = s * (1.0f/256.0f);
  float t = 0.f;
#pragma unroll
  for (int j = 0; j < 4; ++j) { float d = v[j]-m; t += d*d; }
  for (int off = 32; off; off >>= 1) t += __shfl_xor(t, off);
  float r = rsqrtf(t * (1.0f/256.0f) + 1e-5f);
#pragma unroll
  for (int j = 0; j < 4; ++j) {
    const float y = (v[j]-m)*r;
    const size_t o = (size_t)q*256 + lane + 64*j;
    X[o] = y;
    if (oh) { const unsigned short h = f2bf(y); oh[o] = h; ol[o] = f2bf(y - bf2f(h)); }
  }
}

// -------------------------- causal depthwise conv (KC=4) + SiLU ------------
__global__ void conv_kernel(const float* __restrict__ PROJ,
    const float* __restrict__ Wc, const float* __restrict__ bc,
    float* __restrict__ XBC)
{
  const int c = threadIdx.x;      // 640
  const int bt = blockIdx.x;      // 4096
  const int t = bt & 2047;
  float acc = bc[c];
#pragma unroll
  for (int j = 0; j < 4; ++j) {
    int d = j - 3;
    if (t + d >= 0)
      acc = fmaf(PROJ[(size_t)(bt + d)*1160 + 512 + c], Wc[c*4+j], acc);
  }
  XBC[(size_t)bt*640 + c] = acc / (1.f + expf(-acc));  // silu
}

// -------------------------- dt softplus + dA -------------------------------
__global__ void dta_kernel(const float* __restrict__ PROJ,
    const float* __restrict__ dtb, const float* __restrict__ Alog,
    float* __restrict__ Ddt, float* __restrict__ Dda)
{
  const int i = blockIdx.x*256 + threadIdx.x;   // 32768 = 4096*8
  const int bt = i >> 3, hh = i & 7;
  float x = PROJ[(size_t)bt*1160 + 1152 + hh] + dtb[hh];
  float dt = (x > 20.f) ? x : log1pf(expf(x));
  float A = -expf(Alog[hh]);
  Ddt[hh*4096 + bt] = dt;
  Dda[hh*4096 + bt] = expf(dt * A);
}

// -------------------------- scan pass 1: per-chunk S_c, P_c ----------------
__global__ __launch_bounds__(64) void scan1_kernel(
    const float* __restrict__ XBC, const float* __restrict__ Ddt,
    const float* __restrict__ Dda, float* __restrict__ SCH, float* __restrict__ PC)
{
  const int blk = blockIdx.x;
  const int c = blk & 31, hh = (blk >> 5) & 7, b = blk >> 8;
  const int lane = threadIdx.x;
  const int t0 = (b << 11) + (c << 6);
  __shared__ float Bsh[64][64];
  __shared__ float Xsh[64][64];
  __shared__ float dAs[64], dts[64];
#pragma unroll
  for (int it = 0; it < 16; ++it) {
    int idx = it*64 + lane;
    int t = idx >> 4, c4 = (idx & 15) << 2;
    *(float4*)&Bsh[t][c4] = *(const float4*)&XBC[(size_t)(t0 + t)*640 + 512 + c4];
    *(float4*)&Xsh[t][c4] = *(const float4*)&XBC[(size_t)(t0 + t)*640 + (hh<<6) + c4];
  }
  dAs[lane] = Dda[hh*4096 + t0 + lane];
  dts[lane] = Ddt[hh*4096 + t0 + lane];
  __syncthreads();
  float h[64];
#pragma unroll
  for (int s = 0; s < 64; ++s) h[s] = 0.f;
  float p = 1.f;
  for (int t = 0; t < 64; ++t) {
    const float dA = dAs[t];
    const float u = dts[t]*Xsh[t][lane];
    p *= dA;
    const float4* B4 = (const float4*)&Bsh[t][0];
#pragma unroll
    for (int s4 = 0; s4 < 16; ++s4) {
      float4 bv = B4[s4];
      h[4*s4+0] = fmaf(h[4*s4+0], dA, bv.x*u);
      h[4*s4+1] = fmaf(h[4*s4+1], dA, bv.y*u);
      h[4*s4+2] = fmaf(h[4*s4+2], dA, bv.z*u);
      h[4*s4+3] = fmaf(h[4*s4+3], dA, bv.w*u);
    }
  }
  float* op = SCH + (size_t)blk*4096 + lane*64;
#pragma unroll
  for (int s4 = 0; s4 < 16; ++s4)
    ((float4*)op)[s4] = make_float4(h[4*s4], h[4*s4+1], h[4*s4+2], h[4*s4+3]);
  if (lane == 0) PC[blk] = p;
}

// -------------------------- sequential cross-chunk combine (in-place) ------
__global__ void combine_kernel(float* __restrict__ SCH, const float* __restrict__ PC)
{
  const int tid = blockIdx.x*256 + threadIdx.x;   // 65536
  const int bh = tid >> 12, ds = tid & 4095;
  float h = 0.f;
  for (int cc = 0; cc < 32; ++cc) {
    size_t o = ((size_t)(bh*32 + cc) << 12) + ds;
    float s = SCH[o];
    SCH[o] = h;
    h = fmaf(h, PC[bh*32+cc], s);
  }
}

// -------------------------- scan pass 2: exact recurrence + y --------------
__global__ __launch_bounds__(64) void scan2_kernel(
    const float* __restrict__ XBC, const float* __restrict__ Ddt,
    const float* __restrict__ Dda, const float* __restrict__ HST,
    const float* __restrict__ Dm, float* __restrict__ Yout)
{
  const int blk = blockIdx.x;
  const int c = blk & 31, hh = (blk >> 5) & 7, b = blk >> 8;
  const int lane = threadIdx.x;
  const int t0 = (b << 11) + (c << 6);
  __shared__ float Bsh[64][64];
  __shared__ float Csh[64][64];
  __shared__ float Xsh[64][64];
  __shared__ float dAs[64], dts[64];
#pragma unroll
  for (int it = 0; it < 16; ++it) {
    int idx = it*64 + lane;
    int t = idx >> 4, c4 = (idx & 15) << 2;
    *(float4*)&Bsh[t][c4] = *(const float4*)&XBC[(size_t)(t0 + t)*640 + 512 + c4];
    *(float4*)&Csh[t][c4] = *(const float4*)&XBC[(size_t)(t0 + t)*640 + 576 + c4];
    *(float4*)&Xsh[t][c4] = *(const float4*)&XBC[(size_t)(t0 + t)*640 + (hh<<6) + c4];
  }
  dAs[lane] = Dda[hh*4096 + t0 + lane];
  dts[lane] = Ddt[hh*4096 + t0 + lane];
  const float Dh = Dm[hh];
  float h[64];
  const float4* hp = (const float4*)(HST + (size_t)blk*4096 + lane*64);
#pragma unroll
  for (int s4 = 0; s4 < 16; ++s4) {
    float4 t4 = hp[s4];
    h[4*s4+0]=t4.x; h[4*s4+1]=t4.y; h[4*s4+2]=t4.z; h[4*s4+3]=t4.w;
  }
  __syncthreads();
  for (int t = 0; t < 64; ++t) {
    const float dA = dAs[t];
    const float u = dts[t]*Xsh[t][lane];
    float y = 0.f;
    const float4* B4 = (const float4*)&Bsh[t][0];
    const float4* C4 = (const float4*)&Csh[t][0];
#pragma unroll
    for (int s4 = 0; s4 < 16; ++s4) {
      float4 bv = B4[s4];
      float4 cv = C4[s4];
      h[4*s4+0] = fmaf(h[4*s4+0], dA, bv.x*u); y = fmaf(cv.x, h[4*s4+0], y);
      h[4*s4+1] = fmaf(h[4*s4+1], dA, bv.y*u); y = fmaf(cv.y, h[4*s4+1], y);
      h[4*s4+2] = fmaf(h[4*s4+2], dA, bv.z*u); y = fmaf(cv.z, h[4*s4+2], y);
      h[4*s4+3] = fmaf(h[4*s4+3], dA, bv.w*u); y = fmaf(cv.w, h[4*s4+3], y);
    }
    Yout[(size_t)(t0 + t)*512 + (hh<<6) + lane] = y + Dh*Xsh[t][lane];
  }
}

// -------------- gate (silu(z)) + RMSNorm over 512 → Yb bf16 planes ---------
__global__ __launch_bounds__(256) void gaterms_kernel(
    const float* __restrict__ Y, const float* __restrict__ PROJ,
    const float* __restrict__ rmsw,
    unsigned short* __restrict__ Oh, unsigned short* __restrict__ Ol)
{
  const int wave = threadIdx.x >> 6, lane = threadIdx.x & 63;
  const int row = blockIdx.x*4 + wave;   // 4096
  float v[8]; float ss = 0.f;
#pragma unroll
  for (int j = 0; j < 8; ++j) {
    float y = Y[(size_t)row*512 + lane + 64*j];
    float z = PROJ[(size_t)row*1160 + lane + 64*j];
    float g = y * (z / (1.f + expf(-z)));
    v[j] = g; ss += g*g;
  }
  for (int off = 32; off; off >>= 1) ss += __shfl_xor(ss, off);
  float r = rsqrtf(ss * (1.0f/512.0f) + 1e-5f);
#pragma unroll
  for (int j = 0; j < 8; ++j) {
    const float o = v[j] * r * rmsw[lane + 64*j];
    const unsigned short h = f2bf(o);
    const size_t ix = (size_t)row*512 + lane + 64*j;
    Oh[ix] = h; Ol[ix] = f2bf(o - bf2f(h));
  }
}

// ---------------------------------------------------------------------------
extern "C" void kernel_launch(void* const* d_in, const int* in_sizes, int n_in,
                              void* d_out, int out_size, void* d_ws, size_t ws_size,
                              hipStream_t stream)
{
  (void)in_sizes; (void)n_in; (void)out_size; (void)ws_size;
  const float* query = (const float*)d_in[0];
  const float* qpos  = (const float*)d_in[1];
  const float* feats = (const float*)d_in[2];
  const float* spos  = (const float*)d_in[3];
  const float* w_q   = (const float*)d_in[4];
  const float* w_v   = (const float*)d_in[5];
  const float* w_o   = (const float*)d_in[6];
  const float* w_k   = (const float*)d_in[7];
  const float* w_b   = (const float*)d_in[8];
  const float* Win   = (const float*)d_in[9];
  const float* Wconv = (const float*)d_in[10];
  const float* bconv = (const float*)d_in[11];
  const float* Alog  = (const float*)d_in[12];
  const float* Dm    = (const float*)d_in[13];
  const float* dtb   = (const float*)d_in[14];
  const float* rmsw  = (const float*)d_in[15];
  const float* Wout  = (const float*)d_in[16];
  const float* fw1   = (const float*)d_in[17];
  const float* fb1   = (const float*)d_in[18];
  const float* fw2   = (const float*)d_in[19];
  const float* fb2   = (const float*)d_in[20];
  const int*   order = (const int*)d_in[21];
  float* out = (float*)d_out;

  char* ws = (char*)d_ws;
  size_t off = 0;
  auto alloc = [&](size_t bytes) -> void* {
    void* p = ws + off;
    off = (off + bytes + 255) & ~(size_t)255;
    return p;
  };
  int*   IDX = (int*)alloc((size_t)2048*8*4);
  int*   INV = (int*)alloc((size_t)4096*4);
  float* PC  = (float*)alloc((size_t)512*4);
  float4* P4 = (float4*)alloc((size_t)32768*16);
  float* Ddt = (float*)alloc((size_t)4096*8*4);
  float* Dda = (float*)alloc((size_t)4096*8*4);
  float* QP  = (float*)alloc((size_t)2048*256*4);
  float* WO  = (float*)alloc((size_t)2048*256*4);
  float* X   = (float*)alloc((size_t)2048*256*4);
  float* U1  = (float*)alloc((size_t)4096*1160*4);  // PROJ
  float* U2  = (float*)alloc((size_t)4096*640*4);   // XBC
  float* SCH = (float*)alloc((size_t)512*4096*4);   // chunk states
  float* Yb  = (float*)alloc((size_t)4096*512*4);
  float* U6  = (float*)alloc((size_t)4096*256*4);   // OUTL | FFO
  // bf16 split planes
  unsigned short* Qh  = (unsigned short*)alloc((size_t)2048*256*2);
  unsigned short* Ql  = (unsigned short*)alloc((size_t)2048*256*2);
  unsigned short* U7h = (unsigned short*)alloc((size_t)2048*1024*2); // FFH planes
  unsigned short* U7l = (unsigned short*)alloc((size_t)2048*1024*2);
  unsigned short* WBh = (unsigned short*)alloc((size_t)2048*256*2);
  unsigned short* WBl = (unsigned short*)alloc((size_t)2048*256*2);
  unsigned short* XNh = (unsigned short*)alloc((size_t)2048*256*2);  // XN | F planes
  unsigned short* XNl = (unsigned short*)alloc((size_t)2048*256*2);
  unsigned short* Ybh = (unsigned short*)alloc((size_t)4096*512*2);
  unsigned short* Ybl = (unsigned short*)alloc((size_t)4096*512*2);
  unsigned short* Xh  = (unsigned short*)alloc((size_t)2048*256*2);
  unsigned short* Xl  = (unsigned short*)alloc((size_t)2048*256*2);
  unsigned short* Wqh = (unsigned short*)alloc((size_t)256*256*2);
  unsigned short* Wql = (unsigned short*)alloc((size_t)256*256*2);
  unsigned short* Wvh = (unsigned short*)alloc((size_t)256*256*2);
  unsigned short* Wvl = (unsigned short*)alloc((size_t)256*256*2);
  unsigned short* Woh = (unsigned short*)alloc((size_t)256*256*2);
  unsigned short* Wol = (unsigned short*)alloc((size_t)256*256*2);
  unsigned short* Wih = (unsigned short*)alloc((size_t)2*1160*256*2);
  unsigned short* Wil = (unsigned short*)alloc((size_t)2*1160*256*2);
  unsigned short* Wuh = (unsigned short*)alloc((size_t)2*256*512*2);
  unsigned short* Wul = (unsigned short*)alloc((size_t)2*256*512*2);
  unsigned short* F1h = (unsigned short*)alloc((size_t)1024*256*2);
  unsigned short* F1l = (unsigned short*)alloc((size_t)1024*256*2);
  unsigned short* F2h = (unsigned short*)alloc((size_t)256*1024*2);
  unsigned short* F2l = (unsigned short*)alloc((size_t)256*1024*2);
  float* PROJ = U1;
  float* XBC  = U2;
  float* OUTL = U6;  float* FFO  = U6;
  unsigned short* FFHh = U7h;
  unsigned short* FFHl = U7l;

  auto cvt = [&](const float* s, unsigned short* h, unsigned short* l, int n) {
    cvt_kernel<<<(n/4 + 255)/256, 256, 0, stream>>>(s, h, l, n/4);
  };

  // --- stage 1: KNN + aggregation ---
  inv_kernel<<<16, 256, 0, stream>>>(order, INV);
  prep_kernel<<<128, 256, 0, stream>>>(spos, P4);
  knn_kernel<<<2048, 256, 0, stream>>>(qpos, P4, IDX);
  cvt(query, Qh, Ql, 2048*256);
  cvt(w_q, Wqh, Wql, 256*256);
  cvt(w_v, Wvh, Wvl, 256*256);
  cvt(w_o, Woh, Wol, 256*256);
  cvt(Win, Wih, Wil, 2*1160*256);
  cvt(Wout, Wuh, Wul, 2*256*512);
  cvt(fw1, F1h, F1l, 1024*256);
  cvt(fw2, F2h, F2l, 256*1024);
  gemm_mfma<<<dim3(16,4), 256, 0, stream>>>(Qh, Ql, nullptr, Wqh, Wql, nullptr,
                                            nullptr, QP, nullptr, nullptr,
                                            2048,256,256,0);
  // F = sum_k kw_k feats[idx_k]  (linearity: mix before Wv projection)
  kwmix2_kernel<<<512, 256, 0, stream>>>(QP, w_k, w_b, feats, IDX, XNh, XNl);
  // WB = QP ⊙ (F @ Wv^T) — emul epilogue, planes out
  gemm_mfma<<<dim3(16,4), 256, 0, stream>>>(XNh, XNl, nullptr, Wvh, Wvl, nullptr,
                                            QP, nullptr, WBh, WBl,
                                            2048,256,256,0);
  gemm_mfma<<<dim3(16,4), 256, 0, stream>>>(WBh, WBl, nullptr, Woh, Wol, nullptr,
                                            nullptr, WO, nullptr, nullptr,
                                            2048,256,256,0);
  ln_kernel<<<512, 256, 0, stream>>>(WO, query, X, nullptr, nullptr, 2048);

  // --- stage 2: two Mamba2 layers ---
  for (int l = 0; l < 2; ++l) {
    ln_kernel<<<512, 256, 0, stream>>>(X, nullptr, nullptr, XNh, XNl, 2048);
    gemm_mfma<<<dim3(32,19), 256, 0, stream>>>(XNh, XNl, order,
                                               Wih + (size_t)l*1160*256,
                                               Wil + (size_t)l*1160*256,
                                               nullptr, nullptr, PROJ,
                                               nullptr, nullptr,
                                               4096,1160,256,0);
    conv_kernel<<<4096, 640, 0, stream>>>(PROJ, Wconv + l*640*4, bconv + l*640, XBC);
    dta_kernel<<<128, 256, 0, stream>>>(PROJ, dtb + l*8, Alog + l*8, Ddt, Dda);
    scan1_kernel<<<512, 64, 0, stream>>>(XBC, Ddt, Dda, SCH, PC);
    combine_kernel<<<256, 256, 0, stream>>>(SCH, PC);
    scan2_kernel<<<512, 64, 0, stream>>>(XBC, Ddt, Dda, SCH, Dm + l*8, Yb);
    gaterms_kernel<<<1024, 256, 0, stream>>>(Yb, PROJ, rmsw + l*512, Ybh, Ybl);
    gemm_mfma<<<dim3(32,4), 256, 0, stream>>>(Ybh, Ybl, nullptr,
                                              Wuh + (size_t)l*256*512,
                                              Wul + (size_t)l*256*512,
                                              nullptr, nullptr, OUTL,
                                              nullptr, nullptr,
                                              4096,256,512,0);
    ln_unsort_kernel<<<512, 256, 0, stream>>>(OUTL, INV, X,
                                              (l==1) ? Xh : nullptr,
                                              (l==1) ? Xl : nullptr);
  }

  // --- stage 3: FFN ---
  gemm_mfma<<<dim3(16,16), 256, 0, stream>>>(Xh, Xl, nullptr, F1h, F1l, fb1,
                                             nullptr, nullptr, FFHh, FFHl,
                                             2048,1024,256,1);
  gemm_mfma<<<dim3(16,4), 256, 0, stream>>>(FFHh, FFHl, nullptr, F2h, F2l, fb2,
                                            nullptr, FFO, nullptr, nullptr,
                                            2048,256,1024,0);
  ln_kernel<<<512, 256, 0, stream>>>(FFO, X, out, nullptr, nullptr, 2048);
}

// Round 12
// 578.425 us; speedup vs baseline: 1.1392x; 1.0096x over previous
//
#include <hip/hip_runtime.h>
#include <cstdint>

// ---------------------------------------------------------------------------
// LaSSMDecoder on MI355X — Round 12:
//  (a) scan chunk 64→32 (1024 blocks, 2x wave parallelism) + Xsh removed
//      (single-use values preloaded to registers, not LDS).
//  (b) dispatch fusion: 8 cvt → 1 segmented cvt8; dta folded into conv;
//      prep+inv merged. −10 dispatches.
//  (c) round-11 structure otherwise: 128x64 MFMA split GEMM, linearity-
//      factored neighbor mix, producer-side split fusions, KNN @85µs.
// ---------------------------------------------------------------------------

typedef __attribute__((ext_vector_type(8))) short bf16x8;
typedef __attribute__((ext_vector_type(4))) float f32x4;

__device__ __forceinline__ unsigned short f2bf(float f) {
  unsigned int u = __float_as_uint(f);
  u += 0x7fff + ((u >> 16) & 1);        // RNE
  return (unsigned short)(u >> 16);
}
__device__ __forceinline__ float bf2f(unsigned short h) {
  return __uint_as_float(((unsigned int)h) << 16);
}

// -------------------- segmented fp32 -> (hi,lo) bf16 planes ----------------
struct CvtArgs {
  const float* s[8];
  unsigned short* h[8];
  unsigned short* l[8];
  int n4[8];
  int blk0[8];
};
__global__ __launch_bounds__(256) void cvt8_kernel(CvtArgs a)
{
  const int b = blockIdx.x;
  int seg = 0;
#pragma unroll
  for (int j = 1; j < 8; ++j) if (b >= a.blk0[j]) seg = j;
  const int i = (b - a.blk0[seg])*256 + threadIdx.x;
  if (i < a.n4[seg]) {
    const float4 v = ((const float4*)a.s[seg])[i];
    const unsigned short h0=f2bf(v.x), h1=f2bf(v.y), h2=f2bf(v.z), h3=f2bf(v.w);
    const unsigned short l0=f2bf(v.x-bf2f(h0)), l1=f2bf(v.y-bf2f(h1)),
                         l2=f2bf(v.z-bf2f(h2)), l3=f2bf(v.w-bf2f(h3));
    ((uint2*)a.h[seg])[i] = make_uint2((unsigned)h0 | ((unsigned)h1<<16),
                                       (unsigned)h2 | ((unsigned)h3<<16));
    ((uint2*)a.l[seg])[i] = make_uint2((unsigned)l0 | ((unsigned)l1<<16),
                                       (unsigned)l2 | ((unsigned)l3<<16));
  }
}

// ---------------- wave-uniform top-8 list in named registers (float keys) --
__device__ __forceinline__ bool flex_less(float d, int i, float dr, int ir) {
  return d < dr || (d == dr && i < ir);
}

#define KNN_INS_F(dv, iv)                                                      \
  do {                                                                         \
    const float _d = (dv); const int _v = (iv);                                \
    const bool a0 = _d < bd0;                                                  \
    const bool a1 = _d < bd1;                                                  \
    const bool a2 = _d < bd2;                                                  \
    const bool a3 = _d < bd3;                                                  \
    const bool a4 = _d < bd4;                                                  \
    const bool a5 = _d < bd5;                                                  \
    const bool a6 = _d < bd6;                                                  \
    bd7 = a6 ? bd6 : _d;              id7 = a6 ? id6 : _v;                     \
    bd6 = a5 ? bd5 : (a6 ? _d : bd6); id6 = a5 ? id5 : (a6 ? _v : id6);        \
    bd5 = a4 ? bd4 : (a5 ? _d : bd5); id5 = a4 ? id4 : (a5 ? _v : id5);        \
    bd4 = a3 ? bd3 : (a4 ? _d : bd4); id4 = a3 ? id3 : (a4 ? _v : id4);        \
    bd3 = a2 ? bd2 : (a3 ? _d : bd3); id3 = a2 ? id2 : (a3 ? _v : id3);        \
    bd2 = a1 ? bd1 : (a2 ? _d : bd2); id2 = a1 ? id1 : (a2 ? _v : id2);        \
    bd1 = a0 ? bd0 : (a1 ? _d : bd1); id1 = a0 ? id0 : (a1 ? _v : id1);        \
    bd0 = a0 ? _d : bd0;              id0 = a0 ? _v : id0;                     \
  } while (0)

#define KNN_INS_FLEX(dv, iv)                                                   \
  do {                                                                         \
    const float _d = (dv); const int _v = (iv);                                \
    const bool a0 = flex_less(_d, _v, bd0, id0);                               \
    const bool a1 = flex_less(_d, _v, bd1, id1);                               \
    const bool a2 = flex_less(_d, _v, bd2, id2);                               \
    const bool a3 = flex_less(_d, _v, bd3, id3);                               \
    const bool a4 = flex_less(_d, _v, bd4, id4);                               \
    const bool a5 = flex_less(_d, _v, bd5, id5);                               \
    const bool a6 = flex_less(_d, _v, bd6, id6);                               \
    bd7 = a6 ? bd6 : _d;              id7 = a6 ? id6 : _v;                     \
    bd6 = a5 ? bd5 : (a6 ? _d : bd6); id6 = a5 ? id5 : (a6 ? _v : id6);        \
    bd5 = a4 ? bd4 : (a5 ? _d : bd5); id5 = a4 ? id4 : (a5 ? _v : id5);        \
    bd4 = a3 ? bd3 : (a4 ? _d : bd4); id4 = a3 ? id3 : (a4 ? _v : id4);        \
    bd3 = a2 ? bd2 : (a3 ? _d : bd3); id3 = a2 ? id2 : (a3 ? _v : id3);        \
    bd2 = a1 ? bd1 : (a2 ? _d : bd2); id2 = a1 ? id1 : (a2 ? _v : id2);        \
    bd1 = a0 ? bd0 : (a1 ? _d : bd1); id1 = a0 ? id0 : (a1 ? _v : id1);        \
    bd0 = a0 ? _d : bd0;              id0 = a0 ? _v : id0;                     \
  } while (0)

#define KNN_RESET_F()                                                          \
  do {                                                                         \
    bd0=bd1=bd2=bd3=bd4=bd5=bd6=bd7 = 3.4e38f;                                 \
    id0=id1=id2=id3=id4=id5=id6=id7 = 0x7fffffff;                              \
  } while (0)

// -------------------- misc: inverse permutation + point packing ------------
__global__ void misc_kernel(const int* __restrict__ order, int* __restrict__ inv,
                            const float* __restrict__ spos, float4* __restrict__ P4)
{
#pragma clang fp contract(off)
  const int i = blockIdx.x*256 + threadIdx.x;
  if (blockIdx.x < 16) {
    if (i < 4096) { int b = i >> 11, t = i & 2047; inv[(b<<11) + order[i]] = t; }
  } else {
    const int n = i - 4096;
    if (n < 32768) {
      const float sx = spos[n*3+0], sy = spos[n*3+1], sz = spos[n*3+2];
      P4[n] = make_float4(sx, sy, sz, sx*sx + sy*sy + sz*sz);
    }
  }
}

// -------------------------- KNN: 1 query / block, 4 waves ------------------
__global__ __launch_bounds__(256) void knn_kernel(
    const float* __restrict__ qpos, const float4* __restrict__ P4,
    int* __restrict__ idx_out)
{
#pragma clang fp contract(off)
  __shared__ float skey[32];
  __shared__ int   sidx[32];
  const int q = blockIdx.x, tid = threadIdx.x;
  const int wave = tid >> 6, lane = tid & 63;
  const float qx = qpos[q*3+0], qy = qpos[q*3+1], qz = qpos[q*3+2];
  const float qq = qx*qx + qy*qy + qz*qz;
  float bd0,bd1,bd2,bd3,bd4,bd5,bd6,bd7;
  int   id0,id1,id2,id3,id4,id5,id6,id7;
  KNN_RESET_F();
  const float4* pp = P4 + (wave << 13) + lane;   // 8192 pts per wave
  int nb = (wave << 13);
  for (int it = 0; it < 128; ++it) {
    const float4 p = *pp;  pp += 64;
    const float d2 = (qq + p.w) - 2.0f*(qx*p.x + qy*p.y + qz*p.z);  // exact ref formula
    unsigned long long m = __ballot(d2 < bd7);
    while (m) {
      const int l = __ffsll(m) - 1;
      m &= m - 1;
      const float dk = __shfl(d2, l);
      if (dk < bd7) KNN_INS_F(dk, nb + l);
    }
    nb += 64;
  }
  if (lane == 0) {
    const int o = wave*8;
    skey[o+0]=bd0; skey[o+1]=bd1; skey[o+2]=bd2; skey[o+3]=bd3;
    skey[o+4]=bd4; skey[o+5]=bd5; skey[o+6]=bd6; skey[o+7]=bd7;
    sidx[o+0]=id0; sidx[o+1]=id1; sidx[o+2]=id2; sidx[o+3]=id3;
    sidx[o+4]=id4; sidx[o+5]=id5; sidx[o+6]=id6; sidx[o+7]=id7;
  }
  __syncthreads();
  if (tid == 0) {
    KNN_RESET_F();
    for (int s = 0; s < 32; ++s) {
      const float dk = skey[s];
      const int   ui = sidx[s];
      if (flex_less(dk, ui, bd7, id7)) KNN_INS_FLEX(dk, ui);
    }
    idx_out[q*8+0]=id0; idx_out[q*8+1]=id1; idx_out[q*8+2]=id2; idx_out[q*8+3]=id3;
    idx_out[q*8+4]=id4; idx_out[q*8+5]=id5; idx_out[q*8+6]=id6; idx_out[q*8+7]=id7;
  }
}

// -------------------------- MFMA GEMM on pre-split bf16 planes -------------
// Y = act(A[rowmap] @ Wt^T + b) [⊙ emul]; optional (Yh,Yl) plane output.
// Tile 128x64, 4 waves (2x2), per-wave 4x2 frags of 16x16x32, BK=32.
#define GBM 128
#define GBN 64
#define GBK 32
#define GLDK 40   // padded LDS row length (bf16 units): 32 + 8
__global__ __launch_bounds__(256) void gemm_mfma(
    const unsigned short* __restrict__ Ahp, const unsigned short* __restrict__ Alp,
    const int* __restrict__ rowmap,
    const unsigned short* __restrict__ Bhp, const unsigned short* __restrict__ Blp,
    const float* __restrict__ bias, const float* __restrict__ emul,
    float* __restrict__ Y,
    unsigned short* __restrict__ Yh, unsigned short* __restrict__ Yl,
    int M, int Nn, int Kd, int act)
{
  __shared__ unsigned short Ah[GBM*GLDK], Al[GBM*GLDK];
  __shared__ unsigned short Bh[GBN*GLDK], Bl[GBN*GLDK];
  const int tid = threadIdx.x;
  const int bm = blockIdx.x, bn = blockIdx.y;
  const int wid = tid >> 6, lane = tid & 63;
  const int wr = wid >> 1, wc = wid & 1;          // 2x2 wave grid
  const int l15 = lane & 15, lk = (lane >> 4) << 3;

  const int sar = tid >> 1, sak = (tid & 1) << 4;
  const int agrow = bm*GBM + sar;
  const int asrc = rowmap ? rowmap[agrow] : agrow;
  const unsigned short* ArH = Ahp + (size_t)asrc * Kd + sak;
  const unsigned short* ArL = Alp + (size_t)asrc * Kd + sak;
  const int sbr = tid >> 2, sbk = (tid & 3) << 3;
  const int wrow = bn*GBN + sbr;
  const bool bok = (wrow < Nn);
  const unsigned short* BrH = Bhp + (size_t)(bok ? wrow : 0) * Kd + sbk;
  const unsigned short* BrL = Blp + (size_t)(bok ? wrow : 0) * Kd + sbk;

  f32x4 acc[4][2];
#pragma unroll
  for (int m = 0; m < 4; ++m)
#pragma unroll
    for (int n = 0; n < 2; ++n) acc[m][n] = (f32x4){0.f,0.f,0.f,0.f};

  const uint4 z4 = make_uint4(0u,0u,0u,0u);
  for (int k0 = 0; k0 < Kd; k0 += GBK) {
    const int ao = sar*GLDK + sak;
    *(uint4*)&Ah[ao]     = *(const uint4*)(ArH + k0);
    *(uint4*)&Ah[ao + 8] = *(const uint4*)(ArH + k0 + 8);
    *(uint4*)&Al[ao]     = *(const uint4*)(ArL + k0);
    *(uint4*)&Al[ao + 8] = *(const uint4*)(ArL + k0 + 8);
    const int bo = sbr*GLDK + sbk;
    *(uint4*)&Bh[bo] = bok ? *(const uint4*)(BrH + k0) : z4;
    *(uint4*)&Bl[bo] = bok ? *(const uint4*)(BrL + k0) : z4;
    __syncthreads();
    bf16x8 afh[4], afl[4], bfh[2], bfl[2];
#pragma unroll
    for (int m = 0; m < 4; ++m) {
      const int row = wr*64 + m*16 + l15;
      afh[m] = *(const bf16x8*)&Ah[row*GLDK + lk];
      afl[m] = *(const bf16x8*)&Al[row*GLDK + lk];
    }
#pragma unroll
    for (int n = 0; n < 2; ++n) {
      const int row = wc*32 + n*16 + l15;
      bfh[n] = *(const bf16x8*)&Bh[row*GLDK + lk];
      bfl[n] = *(const bf16x8*)&Bl[row*GLDK + lk];
    }
#pragma unroll
    for (int m = 0; m < 4; ++m)
#pragma unroll
      for (int n = 0; n < 2; ++n) {
        acc[m][n] = __builtin_amdgcn_mfma_f32_16x16x32_bf16(afh[m], bfh[n], acc[m][n], 0,0,0);
        acc[m][n] = __builtin_amdgcn_mfma_f32_16x16x32_bf16(afh[m], bfl[n], acc[m][n], 0,0,0);
        acc[m][n] = __builtin_amdgcn_mfma_f32_16x16x32_bf16(afl[m], bfh[n], acc[m][n], 0,0,0);
      }
    __syncthreads();
  }
  const int crow0 = bm*GBM + wr*64 + (lane >> 4)*4;
#pragma unroll
  for (int m = 0; m < 4; ++m) {
#pragma unroll
    for (int n = 0; n < 2; ++n) {
      const int col = bn*GBN + wc*32 + n*16 + l15;
      if (col < Nn) {
#pragma unroll
        for (int r = 0; r < 4; ++r) {
          float v = acc[m][n][r];
          if (bias) v += bias[col];
          if (act == 1) v = 0.5f*v*(1.f + erff(v*0.7071067811865475f));
          const size_t idx = (size_t)(crow0 + m*16 + r)*Nn + col;
          if (emul) v *= emul[idx];
          if (Yh) {
            const unsigned short h = f2bf(v);
            Yh[idx] = h; Yl[idx] = f2bf(v - bf2f(h));
          } else {
            Y[idx] = v;
          }
        }
      }
    }
  }
}

// ------------- kw softmax + fp32 feat gather/mix → F planes ----------------
__global__ __launch_bounds__(256) void kwmix2_kernel(
    const float* __restrict__ QP, const float* __restrict__ wk,
    const float* __restrict__ wb, const float* __restrict__ feats,
    const int* __restrict__ IDX,
    unsigned short* __restrict__ Fh, unsigned short* __restrict__ Fl)
{
  const int wave = threadIdx.x >> 6, lane = threadIdx.x & 63;
  const int q = blockIdx.x*4 + wave;
  float qv[4];
#pragma unroll
  for (int j = 0; j < 4; ++j) qv[j] = QP[(size_t)q*256 + lane + 64*j];
  float logit[8];
#pragma unroll
  for (int k = 0; k < 8; ++k) {
    float p = 0.f;
#pragma unroll
    for (int j = 0; j < 4; ++j) p += qv[j]*wk[k*256 + lane + 64*j];
    for (int off = 32; off; off >>= 1) p += __shfl_xor(p, off);
    logit[k] = p + wb[k];
  }
  float mx = logit[0];
#pragma unroll
  for (int k = 1; k < 8; ++k) mx = fmaxf(mx, logit[k]);
  float e[8]; float s = 0.f;
#pragma unroll
  for (int k = 0; k < 8; ++k) { e[k] = expf(logit[k]-mx); s += e[k]; }
  float inv = 1.f/s;
  float acc[4] = {0.f,0.f,0.f,0.f};
#pragma unroll
  for (int k = 0; k < 8; ++k) {
    const float kwv = e[k]*inv;
    const int ii = IDX[q*8+k];
#pragma unroll
    for (int j = 0; j < 4; ++j)
      acc[j] = fmaf(kwv, feats[(size_t)ii*256 + lane + 64*j], acc[j]);
  }
#pragma unroll
  for (int j = 0; j < 4; ++j) {
    const unsigned short h = f2bf(acc[j]);
    const size_t o = (size_t)q*256 + lane + 64*j;
    Fh[o] = h; Fl[o] = f2bf(acc[j] - bf2f(h));
  }
}

// -------------------------- LayerNorm (fp32 out and/or bf16 planes) --------
__global__ __launch_bounds__(256) void ln_kernel(
    const float* __restrict__ a, const float* __restrict__ b,
    float* __restrict__ out,
    unsigned short* __restrict__ oh, unsigned short* __restrict__ ol,
    int rows)
{
  const int wave = threadIdx.x >> 6, lane = threadIdx.x & 63;
  const int row = blockIdx.x*4 + wave;
  if (row >= rows) return;
  float v[4];
#pragma unroll
  for (int j = 0; j < 4; ++j) {
    float x = a[(size_t)row*256 + lane + 64*j];
    if (b) x += b[(size_t)row*256 + lane + 64*j];
    v[j] = x;
  }
  float s = v[0]+v[1]+v[2]+v[3];
  for (int off = 32; off; off >>= 1) s += __shfl_xor(s, off);
  float m = s * (1.0f/256.0f);
  float t = 0.f;
#pragma unroll
  for (int j = 0; j < 4; ++j) { float d = v[j]-m; t += d*d; }
  for (int off = 32; off; off >>= 1) t += __shfl_xor(t, off);
  float r = rsqrtf(t * (1.0f/256.0f) + 1e-5f);
#pragma unroll
  for (int j = 0; j < 4; ++j) {
    const float y = (v[j]-m)*r;
    const size_t o = (size_t)row*256 + lane + 64*j;
    if (out) out[o] = y;
    if (oh) { const unsigned short h = f2bf(y); oh[o] = h; ol[o] = f2bf(y - bf2f(h)); }
  }
}

// unsort both paths + residual + LN (in-place on X, optional planes)
__global__ __launch_bounds__(256) void ln_unsort_kernel(
    const float* __restrict__ OUTL, const int* __restrict__ INV,
    float* __restrict__ X,
    unsigned short* __restrict__ oh, unsigned short* __restrict__ ol)
{
  const int wave = threadIdx.x >> 6, lane = threadIdx.x & 63;
  const int q = blockIdx.x*4 + wave;
  const int i0 = INV[q], i1 = INV[2048 + q];
  float v[4];
#pragma unroll
  for (int j = 0; j < 4; ++j) {
    int d = lane + 64*j;
    v[j] = X[(size_t)q*256 + d]
         + 0.5f*(OUTL[(size_t)i0*256 + d] + OUTL[(size_t)(2048+i1)*256 + d]);
  }
  float s = v[0]+v[1]+v[2]+v[3];
  for (int off = 32; off; off >>= 1) s += __shfl_xor(s, off);
  float m = s * (1.0f/256.0f);
  float t = 0.f;
#pragma unroll
  for (int j = 0; j < 4; ++j) { float d = v[j]-m; t += d*d; }
  for (int off = 32; off; off >>= 1) t += __shfl_xor(t, off);
  float r = rsqrtf(t * (1.0f/256.0f) + 1e-5f);
#pragma unroll
  for (int j = 0; j < 4; ++j) {
    const float y = (v[j]-m)*r;
    const size_t o = (size_t)q*256 + lane + 64*j;
    X[o] = y;
    if (oh) { const unsigned short h = f2bf(y); oh[o] = h; ol[o] = f2bf(y - bf2f(h)); }
  }
}

// ------------- causal depthwise conv (KC=4) + SiLU, fused dt/dA ------------
__global__ void conv_kernel(const float* __restrict__ PROJ,
    const float* __restrict__ Wc, const float* __restrict__ bc,
    float* __restrict__ XBC,
    const float* __restrict__ dtb, const float* __restrict__ Alog,
    float* __restrict__ Ddt, float* __restrict__ Dda)
{
  const int c = threadIdx.x;      // 640
  const int bt = blockIdx.x;      // 4096
  const int t = bt & 2047;
  float acc = bc[c];
#pragma unroll
  for (int j = 0; j < 4; ++j) {
    int d = j - 3;
    if (t + d >= 0)
      acc = fmaf(PROJ[(size_t)(bt + d)*1160 + 512 + c], Wc[c*4+j], acc);
  }
  XBC[(size_t)bt*640 + c] = acc / (1.f + expf(-acc));  // silu
  if (c < 8) {     // fused dta (reads same PROJ row)
    float x = PROJ[(size_t)bt*1160 + 1152 + c] + dtb[c];
    float dt = (x > 20.f) ? x : log1pf(expf(x));
    float A = -expf(Alog[c]);
    Ddt[c*4096 + bt] = dt;
    Dda[c*4096 + bt] = expf(dt * A);
  }
}

// ------------- scan pass 1 (chunk=32): per-chunk S_c, P_c ------------------
// grid = b(2) * h(8) * chunk(64) = 1024 blocks, 64 threads (lane = d)
__global__ __launch_bounds__(64) void scan1_kernel(
    const float* __restrict__ XBC, const float* __restrict__ Ddt,
    const float* __restrict__ Dda, float* __restrict__ SCH, float* __restrict__ PC)
{
  const int blk = blockIdx.x;
  const int c = blk & 63, hh = (blk >> 6) & 7, b = blk >> 9;
  const int lane = threadIdx.x;
  const int t0 = (b << 11) + (c << 5);
  __shared__ float Bsh[32][64];
  __shared__ float dAs[32], dts[32];
#pragma unroll
  for (int it = 0; it < 8; ++it) {
    int idx = it*64 + lane;
    int t = idx >> 4, c4 = (idx & 15) << 2;
    *(float4*)&Bsh[t][c4] = *(const float4*)&XBC[(size_t)(t0 + t)*640 + 512 + c4];
  }
  if (lane < 32) {
    dAs[lane] = Dda[hh*4096 + t0 + lane];
    dts[lane] = Ddt[hh*4096 + t0 + lane];
  }
  float xv[32];
#pragma unroll
  for (int t = 0; t < 32; ++t)
    xv[t] = XBC[(size_t)(t0 + t)*640 + (hh<<6) + lane];
  __syncthreads();
  float h[64];
#pragma unroll
  for (int s = 0; s < 64; ++s) h[s] = 0.f;
  float p = 1.f;
  for (int t = 0; t < 32; ++t) {
    const float dA = dAs[t];
    const float u = dts[t]*xv[t];
    p *= dA;
    const float4* B4 = (const float4*)&Bsh[t][0];
#pragma unroll
    for (int s4 = 0; s4 < 16; ++s4) {
      float4 bv = B4[s4];
      h[4*s4+0] = fmaf(h[4*s4+0], dA, bv.x*u);
      h[4*s4+1] = fmaf(h[4*s4+1], dA, bv.y*u);
      h[4*s4+2] = fmaf(h[4*s4+2], dA, bv.z*u);
      h[4*s4+3] = fmaf(h[4*s4+3], dA, bv.w*u);
    }
  }
  float* op = SCH + (size_t)blk*4096 + lane*64;
#pragma unroll
  for (int s4 = 0; s4 < 16; ++s4)
    ((float4*)op)[s4] = make_float4(h[4*s4], h[4*s4+1], h[4*s4+2], h[4*s4+3]);
  if (lane == 0) PC[blk] = p;
}

// --------- sequential cross-chunk combine over 64 chunks (in-place) --------
__global__ void combine_kernel(float* __restrict__ SCH, const float* __restrict__ PC)
{
  const int tid = blockIdx.x*256 + threadIdx.x;   // 65536
  const int bh = tid >> 12, ds = tid & 4095;
  float h = 0.f;
  for (int cc = 0; cc < 64; ++cc) {
    size_t o = ((size_t)(bh*64 + cc) << 12) + ds;
    float s = SCH[o];
    SCH[o] = h;
    h = fmaf(h, PC[bh*64+cc], s);
  }
}

// ------------- scan pass 2 (chunk=32): exact recurrence + y ----------------
__global__ __launch_bounds__(64) void scan2_kernel(
    const float* __restrict__ XBC, const float* __restrict__ Ddt,
    const float* __restrict__ Dda, const float* __restrict__ HST,
    const float* __restrict__ Dm, float* __restrict__ Yout)
{
  const int blk = blockIdx.x;
  const int c = blk & 63, hh = (blk >> 6) & 7, b = blk >> 9;
  const int lane = threadIdx.x;
  const int t0 = (b << 11) + (c << 5);
  __shared__ float Bsh[32][64];
  __shared__ float Csh[32][64];
  __shared__ float dAs[32], dts[32];
#pragma unroll
  for (int it = 0; it < 8; ++it) {
    int idx = it*64 + lane;
    int t = idx >> 4, c4 = (idx & 15) << 2;
    *(float4*)&Bsh[t][c4] = *(const float4*)&XBC[(size_t)(t0 + t)*640 + 512 + c4];
    *(float4*)&Csh[t][c4] = *(const float4*)&XBC[(size_t)(t0 + t)*640 + 576 + c4];
  }
  if (lane < 32) {
    dAs[lane] = Dda[hh*4096 + t0 + lane];
    dts[lane] = Ddt[hh*4096 + t0 + lane];
  }
  float xv[32];
#pragma unroll
  for (int t = 0; t < 32; ++t)
    xv[t] = XBC[(size_t)(t0 + t)*640 + (hh<<6) + lane];
  const float Dh = Dm[hh];
  float h[64];
  const float4* hp = (const float4*)(HST + (size_t)blk*4096 + lane*64);
#pragma unroll
  for (int s4 = 0; s4 < 16; ++s4) {
    float4 t4 = hp[s4];
    h[4*s4+0]=t4.x; h[4*s4+1]=t4.y; h[4*s4+2]=t4.z; h[4*s4+3]=t4.w;
  }
  __syncthreads();
  for (int t = 0; t < 32; ++t) {
    const float dA = dAs[t];
    const float u = dts[t]*xv[t];
    float y = 0.f;
    const float4* B4 = (const float4*)&Bsh[t][0];
    const float4* C4 = (const float4*)&Csh[t][0];
#pragma unroll
    for (int s4 = 0; s4 < 16; ++s4) {
      float4 bv = B4[s4];
      float4 cv = C4[s4];
      h[4*s4+0] = fmaf(h[4*s4+0], dA, bv.x*u); y = fmaf(cv.x, h[4*s4+0], y);
      h[4*s4+1] = fmaf(h[4*s4+1], dA, bv.y*u); y = fmaf(cv.y, h[4*s4+1], y);
      h[4*s4+2] = fmaf(h[4*s4+2], dA, bv.z*u); y = fmaf(cv.z, h[4*s4+2], y);
      h[4*s4+3] = fmaf(h[4*s4+3], dA, bv.w*u); y = fmaf(cv.w, h[4*s4+3], y);
    }
    Yout[(size_t)(t0 + t)*512 + (hh<<6) + lane] = y + Dh*xv[t];
  }
}

// -------------- gate (silu(z)) + RMSNorm over 512 → Yb bf16 planes ---------
__global__ __launch_bounds__(256) void gaterms_kernel(
    const float* __restrict__ Y, const float* __restrict__ PROJ,
    const float* __restrict__ rmsw,
    unsigned short* __restrict__ Oh, unsigned short* __restrict__ Ol)
{
  const int wave = threadIdx.x >> 6, lane = threadIdx.x & 63;
  const int row = blockIdx.x*4 + wave;   // 4096
  float v[8]; float ss = 0.f;
#pragma unroll
  for (int j = 0; j < 8; ++j) {
    float y = Y[(size_t)row*512 + lane + 64*j];
    float z = PROJ[(size_t)row*1160 + lane + 64*j];
    float g = y * (z / (1.f + expf(-z)));
    v[j] = g; ss += g*g;
  }
  for (int off = 32; off; off >>= 1) ss += __shfl_xor(ss, off);
  float r = rsqrtf(ss * (1.0f/512.0f) + 1e-5f);
#pragma unroll
  for (int j = 0; j < 8; ++j) {
    const float o = v[j] * r * rmsw[lane + 64*j];
    const unsigned short h = f2bf(o);
    const size_t ix = (size_t)row*512 + lane + 64*j;
    Oh[ix] = h; Ol[ix] = f2bf(o - bf2f(h));
  }
}

// ---------------------------------------------------------------------------
extern "C" void kernel_launch(void* const* d_in, const int* in_sizes, int n_in,
                              void* d_out, int out_size, void* d_ws, size_t ws_size,
                              hipStream_t stream)
{
  (void)in_sizes; (void)n_in; (void)out_size; (void)ws_size;
  const float* query = (const float*)d_in[0];
  const float* qpos  = (const float*)d_in[1];
  const float* feats = (const float*)d_in[2];
  const float* spos  = (const float*)d_in[3];
  const float* w_q   = (const float*)d_in[4];
  const float* w_v   = (const float*)d_in[5];
  const float* w_o   = (const float*)d_in[6];
  const float* w_k   = (const float*)d_in[7];
  const float* w_b   = (const float*)d_in[8];
  const float* Win   = (const float*)d_in[9];
  const float* Wconv = (const float*)d_in[10];
  const float* bconv = (const float*)d_in[11];
  const float* Alog  = (const float*)d_in[12];
  const float* Dm    = (const float*)d_in[13];
  const float* dtb   = (const float*)d_in[14];
  const float* rmsw  = (const float*)d_in[15];
  const float* Wout  = (const float*)d_in[16];
  const float* fw1   = (const float*)d_in[17];
  const float* fb1   = (const float*)d_in[18];
  const float* fw2   = (const float*)d_in[19];
  const float* fb2   = (const float*)d_in[20];
  const int*   order = (const int*)d_in[21];
  float* out = (float*)d_out;

  char* ws = (char*)d_ws;
  size_t off = 0;
  auto alloc = [&](size_t bytes) -> void* {
    void* p = ws + off;
    off = (off + bytes + 255) & ~(size_t)255;
    return p;
  };
  int*   IDX = (int*)alloc((size_t)2048*8*4);
  int*   INV = (int*)alloc((size_t)4096*4);
  float* PC  = (float*)alloc((size_t)1024*4);
  float4* P4 = (float4*)alloc((size_t)32768*16);
  float* Ddt = (float*)alloc((size_t)4096*8*4);
  float* Dda = (float*)alloc((size_t)4096*8*4);
  float* QP  = (float*)alloc((size_t)2048*256*4);
  float* WO  = (float*)alloc((size_t)2048*256*4);
  float* X   = (float*)alloc((size_t)2048*256*4);
  float* U1  = (float*)alloc((size_t)4096*1160*4);  // PROJ
  float* U2  = (float*)alloc((size_t)4096*640*4);   // XBC
  float* SCH = (float*)alloc((size_t)1024*4096*4);  // chunk states (16 MB)
  float* Yb  = (float*)alloc((size_t)4096*512*4);
  float* U6  = (float*)alloc((size_t)4096*256*4);   // OUTL | FFO
  // bf16 split planes
  unsigned short* Qh  = (unsigned short*)alloc((size_t)2048*256*2);
  unsigned short* Ql  = (unsigned short*)alloc((size_t)2048*256*2);
  unsigned short* U7h = (unsigned short*)alloc((size_t)2048*1024*2); // FFH planes
  unsigned short* U7l = (unsigned short*)alloc((size_t)2048*1024*2);
  unsigned short* WBh = (unsigned short*)alloc((size_t)2048*256*2);
  unsigned short* WBl = (unsigned short*)alloc((size_t)2048*256*2);
  unsigned short* XNh = (unsigned short*)alloc((size_t)2048*256*2);  // XN | F planes
  unsigned short* XNl = (unsigned short*)alloc((size_t)2048*256*2);
  unsigned short* Ybh = (unsigned short*)alloc((size_t)4096*512*2);
  unsigned short* Ybl = (unsigned short*)alloc((size_t)4096*512*2);
  unsigned short* Xh  = (unsigned short*)alloc((size_t)2048*256*2);
  unsigned short* Xl  = (unsigned short*)alloc((size_t)2048*256*2);
  unsigned short* Wqh = (unsigned short*)alloc((size_t)256*256*2);
  unsigned short* Wql = (unsigned short*)alloc((size_t)256*256*2);
  unsigned short* Wvh = (unsigned short*)alloc((size_t)256*256*2);
  unsigned short* Wvl = (unsigned short*)alloc((size_t)256*256*2);
  unsigned short* Woh = (unsigned short*)alloc((size_t)256*256*2);
  unsigned short* Wol = (unsigned short*)alloc((size_t)256*256*2);
  unsigned short* Wih = (unsigned short*)alloc((size_t)2*1160*256*2);
  unsigned short* Wil = (unsigned short*)alloc((size_t)2*1160*256*2);
  unsigned short* Wuh = (unsigned short*)alloc((size_t)2*256*512*2);
  unsigned short* Wul = (unsigned short*)alloc((size_t)2*256*512*2);
  unsigned short* F1h = (unsigned short*)alloc((size_t)1024*256*2);
  unsigned short* F1l = (unsigned short*)alloc((size_t)1024*256*2);
  unsigned short* F2h = (unsigned short*)alloc((size_t)256*1024*2);
  unsigned short* F2l = (unsigned short*)alloc((size_t)256*1024*2);
  float* PROJ = U1;
  float* XBC  = U2;
  float* OUTL = U6;  float* FFO  = U6;
  unsigned short* FFHh = U7h;
  unsigned short* FFHl = U7l;

  // --- stage 1: KNN + aggregation ---
  misc_kernel<<<144, 256, 0, stream>>>(order, INV, spos, P4);
  knn_kernel<<<2048, 256, 0, stream>>>(qpos, P4, IDX);
  // one segmented cvt for query + all weights
  CvtArgs ca;
  ca.s[0]=query; ca.h[0]=Qh;  ca.l[0]=Ql;  ca.n4[0]=131072; ca.blk0[0]=0;
  ca.s[1]=w_q;   ca.h[1]=Wqh; ca.l[1]=Wql; ca.n4[1]=16384;  ca.blk0[1]=512;
  ca.s[2]=w_v;   ca.h[2]=Wvh; ca.l[2]=Wvl; ca.n4[2]=16384;  ca.blk0[2]=576;
  ca.s[3]=w_o;   ca.h[3]=Woh; ca.l[3]=Wol; ca.n4[3]=16384;  ca.blk0[3]=640;
  ca.s[4]=Win;   ca.h[4]=Wih; ca.l[4]=Wil; ca.n4[4]=148480; ca.blk0[4]=704;
  ca.s[5]=Wout;  ca.h[5]=Wuh; ca.l[5]=Wul; ca.n4[5]=65536;  ca.blk0[5]=1284;
  ca.s[6]=fw1;   ca.h[6]=F1h; ca.l[6]=F1l; ca.n4[6]=65536;  ca.blk0[6]=1540;
  ca.s[7]=fw2;   ca.h[7]=F2h; ca.l[7]=F2l; ca.n4[7]=65536;  ca.blk0[7]=1796;
  cvt8_kernel<<<2052, 256, 0, stream>>>(ca);
  gemm_mfma<<<dim3(16,4), 256, 0, stream>>>(Qh, Ql, nullptr, Wqh, Wql, nullptr,
                                            nullptr, QP, nullptr, nullptr,
                                            2048,256,256,0);
  kwmix2_kernel<<<512, 256, 0, stream>>>(QP, w_k, w_b, feats, IDX, XNh, XNl);
  gemm_mfma<<<dim3(16,4), 256, 0, stream>>>(XNh, XNl, nullptr, Wvh, Wvl, nullptr,
                                            QP, nullptr, WBh, WBl,
                                            2048,256,256,0);
  gemm_mfma<<<dim3(16,4), 256, 0, stream>>>(WBh, WBl, nullptr, Woh, Wol, nullptr,
                                            nullptr, WO, nullptr, nullptr,
                                            2048,256,256,0);
  ln_kernel<<<512, 256, 0, stream>>>(WO, query, X, nullptr, nullptr, 2048);

  // --- stage 2: two Mamba2 layers ---
  for (int l = 0; l < 2; ++l) {
    ln_kernel<<<512, 256, 0, stream>>>(X, nullptr, nullptr, XNh, XNl, 2048);
    gemm_mfma<<<dim3(32,19), 256, 0, stream>>>(XNh, XNl, order,
                                               Wih + (size_t)l*1160*256,
                                               Wil + (size_t)l*1160*256,
                                               nullptr, nullptr, PROJ,
                                               nullptr, nullptr,
                                               4096,1160,256,0);
    conv_kernel<<<4096, 640, 0, stream>>>(PROJ, Wconv + l*640*4, bconv + l*640,
                                          XBC, dtb + l*8, Alog + l*8, Ddt, Dda);
    scan1_kernel<<<1024, 64, 0, stream>>>(XBC, Ddt, Dda, SCH, PC);
    combine_kernel<<<256, 256, 0, stream>>>(SCH, PC);
    scan2_kernel<<<1024, 64, 0, stream>>>(XBC, Ddt, Dda, SCH, Dm + l*8, Yb);
    gaterms_kernel<<<1024, 256, 0, stream>>>(Yb, PROJ, rmsw + l*512, Ybh, Ybl);
    gemm_mfma<<<dim3(32,4), 256, 0, stream>>>(Ybh, Ybl, nullptr,
                                              Wuh + (size_t)l*256*512,
                                              Wul + (size_t)l*256*512,
                                              nullptr, nullptr, OUTL,
                                              nullptr, nullptr,
                                              4096,256,512,0);
    ln_unsort_kernel<<<512, 256, 0, stream>>>(OUTL, INV, X,
                                              (l==1) ? Xh : nullptr,
                                              (l==1) ? Xl : nullptr);
  }

  // --- stage 3: FFN ---
  gemm_mfma<<<dim3(16,16), 256, 0, stream>>>(Xh, Xl, nullptr, F1h, F1l, fb1,
                                             nullptr, nullptr, FFHh, FFHl,
                                             2048,1024,256,1);
  gemm_mfma<<<dim3(16,4), 256, 0, stream>>>(FFHh, FFHl, nullptr, F2h, F2l, fb2,
                                            nullptr, FFO, nullptr, nullptr,
                                            2048,256,1024,0);
  ln_kernel<<<512, 256, 0, stream>>>(FFO, X, out, nullptr, nullptr, 2048);
}